// Round 11
// baseline (2555.774 us; speedup 1.0000x reference)
//
#include <hip/hip_runtime.h>
#include <hip/hip_bf16.h>

typedef __bf16 bf16;
typedef _Float16 fp16;
typedef __attribute__((ext_vector_type(8))) __bf16 bf16x8;
typedef __attribute__((ext_vector_type(4))) __bf16 bf16x4;
typedef __attribute__((ext_vector_type(2))) _Float16 fp16x2;
typedef __attribute__((ext_vector_type(4))) float f32x4;

#define H_IN 1342
#define TT   128
#define BB   128

static __device__ __forceinline__ f32x4 mfma16(bf16x8 a, bf16x8 b, f32x4 c) {
    return __builtin_amdgcn_mfma_f32_16x16x32_bf16(a, b, c, 0, 0, 0);
}
static __device__ __forceinline__ float sigf(float x) {
    return 1.f / (1.f + __expf(-x));
}
static __device__ __forceinline__ float tanhfast(float x) {
    return 2.f / (1.f + __expf(-2.f * x)) - 1.f;
}

// ---------------------------------------------------------------------------
// Pack the three w_hh matrices (768x256) into MFMA B-fragment order.
// (round-6 verified)
// ---------------------------------------------------------------------------
__global__ void prep_pack2(const float* __restrict__ whh0,
                           const float* __restrict__ whh1,
                           const float* __restrict__ whh2,
                           bf16* __restrict__ Wh)
{
    int idx = blockIdx.x * blockDim.x + threadIdx.x;
    if (idx < 589824) {
        int l = idx / 196608;
        int r = idx - l * 196608;
        const float* w = (l == 0) ? whh0 : (l == 1) ? whh1 : whh2;
        int f = r >> 9, q = r & 511;
        int lane = q >> 3, j = q & 7;
        int nt = f >> 3, kt = f & 7;
        int n = nt * 16 + (lane & 15);
        int k = kt * 32 + (lane >> 4) * 8 + j;
        Wh[idx] = (bf16)w[n * 256 + k];
    }
}

// ---------------------------------------------------------------------------
// Layer-0 input GEMM. Epilogue: r,z -> interleaved fp16x2 dword plane
// (lo=r, hi=z, b_hh folded), n -> fp32 plane. (round-6..10 verified)
// ---------------------------------------------------------------------------
__global__ __launch_bounds__(512) void gemm_gx0(const float* __restrict__ X,
                                                const float* __restrict__ W,
                                                const float* __restrict__ bih,
                                                const float* __restrict__ bhh,
                                                char*  __restrict__ gxrz2b,
                                                float* __restrict__ gxn)
{
    __shared__ bf16 As[128][40];
    __shared__ bf16 Bs[256][40];
    const int tid  = threadIdx.x;
    const int lane = tid & 63;
    const int w    = tid >> 6;
    const int cl   = lane & 15;
    const int lh   = lane >> 4;
    const int rm0  = blockIdx.x * 128;
    const int n0   = blockIdx.y * 256;

    f32x4 acc[16];
#pragma unroll
    for (int i = 0; i < 16; ++i) acc[i] = (f32x4){0.f, 0.f, 0.f, 0.f};

    for (int kt = 0; kt < 42; ++kt) {
        const int k0 = kt * 32;
        {
            int row = tid >> 2;
            int c   = (tid & 3) * 8;
            const float* src = X + (size_t)(rm0 + row) * H_IN + (k0 + c);
            bf16x8 pk;
            if (k0 + c + 8 <= H_IN) {
                const float2* s2 = (const float2*)src;
                float2 v0 = s2[0], v1 = s2[1], v2 = s2[2], v3 = s2[3];
                pk[0] = (bf16)v0.x; pk[1] = (bf16)v0.y; pk[2] = (bf16)v1.x; pk[3] = (bf16)v1.y;
                pk[4] = (bf16)v2.x; pk[5] = (bf16)v2.y; pk[6] = (bf16)v3.x; pk[7] = (bf16)v3.y;
            } else {
#pragma unroll
                for (int i = 0; i < 8; ++i)
                    pk[i] = (bf16)((k0 + c + i < H_IN) ? src[i] : 0.f);
            }
            *(bf16x8*)&As[row][c] = pk;
        }
        {
            int row = tid >> 1;
            int c   = (tid & 1) * 16;
            const float* src = W + (size_t)(n0 + row) * H_IN + (k0 + c);
#pragma unroll
            for (int h = 0; h < 2; ++h) {
                const float* s = src + h * 8;
                bf16x8 pk;
                if (k0 + c + h * 8 + 8 <= H_IN) {
                    const float2* s2 = (const float2*)s;
                    float2 v0 = s2[0], v1 = s2[1], v2 = s2[2], v3 = s2[3];
                    pk[0] = (bf16)v0.x; pk[1] = (bf16)v0.y; pk[2] = (bf16)v1.x; pk[3] = (bf16)v1.y;
                    pk[4] = (bf16)v2.x; pk[5] = (bf16)v2.y; pk[6] = (bf16)v3.x; pk[7] = (bf16)v3.y;
                } else {
#pragma unroll
                    for (int i = 0; i < 8; ++i)
                        pk[i] = (bf16)((k0 + c + h * 8 + i < H_IN) ? s[i] : 0.f);
                }
                *(bf16x8*)&Bs[row][c + h * 8] = pk;
            }
        }
        __syncthreads();
        bf16x8 a = *(const bf16x8*)&As[w * 16 + cl][lh * 8];
#pragma unroll
        for (int nt = 0; nt < 16; ++nt) {
            bf16x8 b = *(const bf16x8*)&Bs[nt * 16 + cl][lh * 8];
            acc[nt] = mfma16(a, b, acc[nt]);
        }
        __syncthreads();
    }
#pragma unroll
    for (int nt = 0; nt < 16; ++nt) {
#pragma unroll
        for (int r = 0; r < 4; ++r) {
            int rm  = rm0 + w * 16 + 4 * lh + r;
            int col = n0 + nt * 16 + cl;
            int b = rm >> 7, t = rm & 127;          // X rows are b*128+t
            size_t ro = (size_t)t * BB + b;
            if (col < 512) {
                float v = acc[nt][r] + bih[col] + bhh[col];
                *(fp16*)(gxrz2b + ro * 1024 + (col & 255) * 4 + (col >> 8) * 2) = (fp16)v;
            } else {
                gxn[ro * 256 + (col - 512)] = acc[nt][r] + bih[col];
            }
        }
    }
}

// ---------------------------------------------------------------------------
// Layers 1/2 input GEMM: same epilogue; A = Y bf16 [t*128+b][256].
// ---------------------------------------------------------------------------
__global__ __launch_bounds__(512) void gemm_gxy(const bf16* __restrict__ Y,
                                                const float* __restrict__ W,
                                                const float* __restrict__ bih,
                                                const float* __restrict__ bhh,
                                                char*  __restrict__ gxrz2b,
                                                float* __restrict__ gxn)
{
    __shared__ bf16 As[128][40];
    __shared__ bf16 Bs[256][40];
    const int tid  = threadIdx.x;
    const int lane = tid & 63;
    const int w    = tid >> 6;
    const int cl   = lane & 15;
    const int lh   = lane >> 4;
    const int rm0  = blockIdx.x * 128;
    const int n0   = blockIdx.y * 256;

    f32x4 acc[16];
#pragma unroll
    for (int i = 0; i < 16; ++i) acc[i] = (f32x4){0.f, 0.f, 0.f, 0.f};

    for (int kt = 0; kt < 8; ++kt) {
        const int k0 = kt * 32;
        {
            int row = tid >> 2;
            int c   = (tid & 3) * 8;
            *(bf16x8*)&As[row][c] =
                *(const bf16x8*)(Y + (size_t)(rm0 + row) * 256 + k0 + c);
        }
        {
            int row = tid >> 1;
            int c   = (tid & 1) * 16;
            const float* src = W + (size_t)(n0 + row) * 256 + (k0 + c);
#pragma unroll
            for (int h = 0; h < 2; ++h) {
                const float2* s2 = (const float2*)(src + h * 8);
                float2 v0 = s2[0], v1 = s2[1], v2 = s2[2], v3 = s2[3];
                bf16x8 pk;
                pk[0] = (bf16)v0.x; pk[1] = (bf16)v0.y; pk[2] = (bf16)v1.x; pk[3] = (bf16)v1.y;
                pk[4] = (bf16)v2.x; pk[5] = (bf16)v2.y; pk[6] = (bf16)v3.x; pk[7] = (bf16)v3.y;
                *(bf16x8*)&Bs[row][c + h * 8] = pk;
            }
        }
        __syncthreads();
        bf16x8 a = *(const bf16x8*)&As[w * 16 + cl][lh * 8];
#pragma unroll
        for (int nt = 0; nt < 16; ++nt) {
            bf16x8 b = *(const bf16x8*)&Bs[nt * 16 + cl][lh * 8];
            acc[nt] = mfma16(a, b, acc[nt]);
        }
        __syncthreads();
    }
#pragma unroll
    for (int nt = 0; nt < 16; ++nt) {
#pragma unroll
        for (int r = 0; r < 4; ++r) {
            size_t rm = (size_t)(rm0 + w * 16 + 4 * lh + r);   // = t*128 + b
            int col = n0 + nt * 16 + cl;
            if (col < 512) {
                float v = acc[nt][r] + bih[col] + bhh[col];
                *(fp16*)(gxrz2b + rm * 1024 + (col & 255) * 4 + (col >> 8) * 2) = (fp16)v;
            } else {
                gxn[rm * 256 + (col - 512)] = acc[nt][r] + bih[col];
            }
        }
    }
}

// ---------------------------------------------------------------------------
// Recurrent layer v6: 8 blocks x 1024 threads (16 waves/CU, 4/SIMD, VGPR
// cap 128). Wave w owns exactly ONE col-tile (w) x 3 gates = 24 B-frags =
// 96 VGPRs -> full 384 KB weight set register-resident across the CU.
// gx staged to LDS by global_load_lds ring (counted vmcnt, never 0);
// raw s_barrier with lgkm-only drains; vectorized Y epilogue.
// ---------------------------------------------------------------------------
__global__ __launch_bounds__(1024, 4) void gru_rec(
    const unsigned int* __restrict__ grzp,  // [T*B][256] dwords: (fp16 r, fp16 z)
    const float* __restrict__ gxn,          // [T*B][256] fp32 (n, incl b_ih)
    const bf16*  __restrict__ Wh,           // this layer's hh pack
    const float* __restrict__ bhh,          // raw b_hh (768); only n-part used
    const float* __restrict__ h0,           // hidden + l*128*256
    bf16*  __restrict__ Y,                  // [T*B][256] bf16 out
    float* __restrict__ hnfL)               // hnf + l*256 (stride 768)
{
    __shared__ bf16 Ah[16][264];
    __shared__ __align__(16) char gxl[2][2][16][1040];  // [slot][rz|n][row][1KB+16 pad]

    const int tid  = threadIdx.x;           // 0..1023
    const int lane = tid & 63;
    const int w    = tid >> 6;              // 0..15 == col-tile index
    const int cl   = lane & 15;
    const int lh   = lane >> 4;
    const int g    = blockIdx.x;
    const int col  = w * 16 + cl;

    // ---- 24 B-fragments (one col-tile, 3 gates) -> registers ----
    bf16x8 Br[8], Bz[8], Bn[8];
#pragma unroll
    for (int kk = 0; kk < 8; ++kk) {
        Br[kk] = *(const bf16x8*)(Wh + (size_t)(( w       * 8 + kk) * 512) + lane * 8);
        Bz[kk] = *(const bf16x8*)(Wh + (size_t)(((16 + w) * 8 + kk) * 512) + lane * 8);
        Bn[kk] = *(const bf16x8*)(Wh + (size_t)(((32 + w) * 8 + kk) * 512) + lane * 8);
    }
    const float bN = bhh[512 + col];

    // gx tile stage: wave w stages row w of both planes (DMA, 16B/lane)
    auto STAGE = [&](int tt, int slot) {
        const size_t gr = (size_t)tt * BB + g * 16 + w;
        const unsigned int* s0 = grzp + gr * 256 + lane * 4;
        const float*        s1 = gxn  + gr * 256 + lane * 4;
        __builtin_amdgcn_global_load_lds(
            (const __attribute__((address_space(1))) void*)s0,
            (__attribute__((address_space(3))) void*)&gxl[slot][0][w][0], 16, 0, 0);
        __builtin_amdgcn_global_load_lds(
            (const __attribute__((address_space(1))) void*)s1,
            (__attribute__((address_space(3))) void*)&gxl[slot][1][w][0], 16, 0, 0);
    };

    // ---- prologue: h0 -> regs + Ah; issue tile 0 ----
    float hprev[4];
#pragma unroll
    for (int r = 0; r < 4; ++r) {
        const int m = 4 * lh + r;
        float v = h0[(size_t)(g * 16 + m) * 256 + col];
        hprev[r] = v;
        Ah[m][col] = (bf16)v;
    }
    STAGE(0, 0);
    __syncthreads();   // one-time full drain (tile 0 + Ah staged)

    for (int t = 0; t < TT; ++t) {
        const int slot = t & 1;
        // ---- phase 1: issue next tile, MFMA over Ah ----
        STAGE((t + 1 < TT) ? t + 1 : TT - 1, slot ^ 1);
        f32x4 cr = (f32x4){0.f,0.f,0.f,0.f};
        f32x4 cz = (f32x4){0.f,0.f,0.f,0.f};
        f32x4 cn = (f32x4){0.f,0.f,0.f,0.f};
#pragma unroll
        for (int kk = 0; kk < 8; ++kk) {
            bf16x8 a = *(const bf16x8*)&Ah[cl][kk * 32 + lh * 8];
            cr = mfma16(a, Br[kk], cr);
            cz = mfma16(a, Bz[kk], cz);
            cn = mfma16(a, Bn[kk], cn);
        }
        asm volatile("s_waitcnt lgkmcnt(0)" ::: "memory");
        __builtin_amdgcn_sched_barrier(0);
        __builtin_amdgcn_s_barrier();          // A: all Ah reads done
        __builtin_amdgcn_sched_barrier(0);

        // ---- tile t ready? newer ops: (t>0: 1 Y-store) + 2 next-tile loads ----
        if (t == 0) asm volatile("s_waitcnt vmcnt(2)" ::: "memory");
        else        asm volatile("s_waitcnt vmcnt(3)" ::: "memory");
        __builtin_amdgcn_sched_barrier(0);

        // ---- gates: gx from LDS, h update, Ah write ----
#pragma unroll
        for (int r = 0; r < 4; ++r) {
            const int m = 4 * lh + r;
            unsigned int rzu = *(const unsigned int*)&gxl[slot][0][m][col * 4];
            float gnv        = *(const float*)       &gxl[slot][1][m][col * 4];
            fp16x2 rz = __builtin_bit_cast(fp16x2, rzu);
            float rr_ = sigf((float)rz[0] + cr[r]);
            float zz  = sigf((float)rz[1] + cz[r]);
            float nn  = tanhfast(gnv + rr_ * (cn[r] + bN));
            float hnew = (1.f - zz) * nn + zz * hprev[r];
            hprev[r] = hnew;
            Ah[m][col] = (bf16)hnew;
            if (t == TT - 1) hnfL[(size_t)(g * 16 + m) * 768 + col] = hnew;
        }
        asm volatile("s_waitcnt lgkmcnt(0)" ::: "memory");
        __builtin_amdgcn_sched_barrier(0);
        __builtin_amdgcn_s_barrier();          // B: Ah writes visible
        __builtin_amdgcn_sched_barrier(0);

        // ---- vectorized Y epilogue (store stays in flight) ----
        {
            const int yrow = tid >> 6;          // 0..15
            const int yc   = (tid & 63) * 4;    // 0..252
            bf16x4 yv = *(const bf16x4*)&Ah[yrow][yc];
            *(bf16x4*)(Y + ((size_t)t * BB + g * 16 + yrow) * 256 + yc) = yv;
        }
    }
}

// ---------------------------------------------------------------------------
__global__ __launch_bounds__(256) void fc_out(const float* __restrict__ hn,
                                              const float* __restrict__ fcw,
                                              const float* __restrict__ fcb,
                                              float* __restrict__ out)
{
    __shared__ float hs[768];
    const int b = blockIdx.x;
    for (int i = threadIdx.x; i < 768; i += 256) hs[i] = hn[(size_t)b * 768 + i];
    __syncthreads();
    for (int i = threadIdx.x; i < H_IN; i += 256) {
        const float4* wr = (const float4*)(fcw + (size_t)i * 768);
        float a0 = 0.f, a1 = 0.f, a2 = 0.f, a3 = 0.f;
#pragma unroll 4
        for (int c = 0; c < 192; ++c) {
            float4 wv = wr[c];
            const float* h4 = &hs[c * 4];
            a0 += wv.x * h4[0]; a1 += wv.y * h4[1];
            a2 += wv.z * h4[2]; a3 += wv.w * h4[3];
        }
        out[(size_t)b * H_IN + i] = fcb[i] + a0 + a1 + a2 + a3;
    }
}

extern "C" void kernel_launch(void* const* d_in, const int* in_sizes, int n_in,
                              void* d_out, int out_size, void* d_ws, size_t ws_size,
                              hipStream_t stream) {
    const float* X    = (const float*)d_in[0];
    const float* hid  = (const float*)d_in[1];
    const float* wih0 = (const float*)d_in[2];
    const float* whh0 = (const float*)d_in[3];
    const float* bih0 = (const float*)d_in[4];
    const float* bhh0 = (const float*)d_in[5];
    const float* wih1 = (const float*)d_in[6];
    const float* whh1 = (const float*)d_in[7];
    const float* bih1 = (const float*)d_in[8];
    const float* bhh1 = (const float*)d_in[9];
    const float* wih2 = (const float*)d_in[10];
    const float* whh2 = (const float*)d_in[11];
    const float* bih2 = (const float*)d_in[12];
    const float* bhh2 = (const float*)d_in[13];
    const float* fcw  = (const float*)d_in[14];
    const float* fcb  = (const float*)d_in[15];
    float* out = (float*)d_out;

    // Layout (total 43,525,120 B — within the known-safe 52.7 MB):
    char* ws = (char*)d_ws;
    bf16*  Wh    = (bf16*)ws;                      //          0 .. 1,179,648
    float* hnf   = (float*)(ws + 1188864);         //  1,188,864 .. 1,582,080
    bf16*  Y     = (bf16*)(ws + 1582080);          //  1,582,080 .. 9,970,688
    float* gxn   = (float*)(ws + 9970688);         //  9,970,688 .. 26,747,904
    char*  gxrzb = ws + 26747904;                  // 26,747,904 .. 43,525,120
    const unsigned int* grzp = (const unsigned int*)gxrzb;

    prep_pack2<<<dim3(1152), dim3(512), 0, stream>>>(whh0, whh1, whh2, Wh);
    // layer 0
    gemm_gx0<<<dim3(128, 3), dim3(512), 0, stream>>>(X, wih0, bih0, bhh0, gxrzb, gxn);
    gru_rec<<<dim3(8), dim3(1024), 0, stream>>>(grzp, gxn, Wh, bhh0,
                                                hid, Y, hnf);
    // layer 1
    gemm_gxy<<<dim3(128, 3), dim3(512), 0, stream>>>(Y, wih1, bih1, bhh1, gxrzb, gxn);
    gru_rec<<<dim3(8), dim3(1024), 0, stream>>>(grzp, gxn, Wh + 196608, bhh1,
                                                hid + 32768, Y, hnf + 256);
    // layer 2
    gemm_gxy<<<dim3(128, 3), dim3(512), 0, stream>>>(Y, wih2, bih2, bhh2, gxrzb, gxn);
    gru_rec<<<dim3(8), dim3(1024), 0, stream>>>(grzp, gxn, Wh + 393216, bhh2,
                                                hid + 65536, Y, hnf + 512);
    // head
    fc_out<<<dim3(128), dim3(256), 0, stream>>>(hnf, fcw, fcb, out);
    hipMemcpyAsync(out + 171776, hid, 98304 * sizeof(float),
                   hipMemcpyDeviceToDevice, stream);
}

// Round 12
// 1805.325 us; speedup vs baseline: 1.4157x; 1.4157x over previous
//
#include <hip/hip_runtime.h>
#include <hip/hip_bf16.h>

typedef __bf16 bf16;
typedef _Float16 fp16;
typedef __attribute__((ext_vector_type(8))) __bf16 bf16x8;
typedef __attribute__((ext_vector_type(2))) _Float16 fp16x2;
typedef __attribute__((ext_vector_type(4))) float f32x4;

#define H_IN 1342
#define TT   128
#define BB   128

static __device__ __forceinline__ f32x4 mfma16(bf16x8 a, bf16x8 b, f32x4 c) {
    return __builtin_amdgcn_mfma_f32_16x16x32_bf16(a, b, c, 0, 0, 0);
}
static __device__ __forceinline__ float sigf(float x) {
    return 1.f / (1.f + __expf(-x));
}
static __device__ __forceinline__ float tanhfast(float x) {
    return 2.f / (1.f + __expf(-2.f * x)) - 1.f;
}

// ---------------------------------------------------------------------------
// Pack the three w_hh matrices (768x256) into MFMA B-fragment order.
// (round-6 verified)
// ---------------------------------------------------------------------------
__global__ void prep_pack2(const float* __restrict__ whh0,
                           const float* __restrict__ whh1,
                           const float* __restrict__ whh2,
                           bf16* __restrict__ Wh)
{
    int idx = blockIdx.x * blockDim.x + threadIdx.x;
    if (idx < 589824) {
        int l = idx / 196608;
        int r = idx - l * 196608;
        const float* w = (l == 0) ? whh0 : (l == 1) ? whh1 : whh2;
        int f = r >> 9, q = r & 511;
        int lane = q >> 3, j = q & 7;
        int nt = f >> 3, kt = f & 7;
        int n = nt * 16 + (lane & 15);
        int k = kt * 32 + (lane >> 4) * 8 + j;
        Wh[idx] = (bf16)w[n * 256 + k];
    }
}

// ---------------------------------------------------------------------------
// Layer-0 input GEMM. Epilogue: r,z -> interleaved fp16x2 dword plane
// (lo=r, hi=z, b_hh folded), n -> fp32 plane. (round-6..11 verified)
// ---------------------------------------------------------------------------
__global__ __launch_bounds__(512) void gemm_gx0(const float* __restrict__ X,
                                                const float* __restrict__ W,
                                                const float* __restrict__ bih,
                                                const float* __restrict__ bhh,
                                                char*  __restrict__ gxrz2b,
                                                float* __restrict__ gxn)
{
    __shared__ bf16 As[128][40];
    __shared__ bf16 Bs[256][40];
    const int tid  = threadIdx.x;
    const int lane = tid & 63;
    const int w    = tid >> 6;
    const int cl   = lane & 15;
    const int lh   = lane >> 4;
    const int rm0  = blockIdx.x * 128;
    const int n0   = blockIdx.y * 256;

    f32x4 acc[16];
#pragma unroll
    for (int i = 0; i < 16; ++i) acc[i] = (f32x4){0.f, 0.f, 0.f, 0.f};

    for (int kt = 0; kt < 42; ++kt) {
        const int k0 = kt * 32;
        {
            int row = tid >> 2;
            int c   = (tid & 3) * 8;
            const float* src = X + (size_t)(rm0 + row) * H_IN + (k0 + c);
            bf16x8 pk;
            if (k0 + c + 8 <= H_IN) {
                const float2* s2 = (const float2*)src;
                float2 v0 = s2[0], v1 = s2[1], v2 = s2[2], v3 = s2[3];
                pk[0] = (bf16)v0.x; pk[1] = (bf16)v0.y; pk[2] = (bf16)v1.x; pk[3] = (bf16)v1.y;
                pk[4] = (bf16)v2.x; pk[5] = (bf16)v2.y; pk[6] = (bf16)v3.x; pk[7] = (bf16)v3.y;
            } else {
#pragma unroll
                for (int i = 0; i < 8; ++i)
                    pk[i] = (bf16)((k0 + c + i < H_IN) ? src[i] : 0.f);
            }
            *(bf16x8*)&As[row][c] = pk;
        }
        {
            int row = tid >> 1;
            int c   = (tid & 1) * 16;
            const float* src = W + (size_t)(n0 + row) * H_IN + (k0 + c);
#pragma unroll
            for (int h = 0; h < 2; ++h) {
                const float* s = src + h * 8;
                bf16x8 pk;
                if (k0 + c + h * 8 + 8 <= H_IN) {
                    const float2* s2 = (const float2*)s;
                    float2 v0 = s2[0], v1 = s2[1], v2 = s2[2], v3 = s2[3];
                    pk[0] = (bf16)v0.x; pk[1] = (bf16)v0.y; pk[2] = (bf16)v1.x; pk[3] = (bf16)v1.y;
                    pk[4] = (bf16)v2.x; pk[5] = (bf16)v2.y; pk[6] = (bf16)v3.x; pk[7] = (bf16)v3.y;
                } else {
#pragma unroll
                    for (int i = 0; i < 8; ++i)
                        pk[i] = (bf16)((k0 + c + h * 8 + i < H_IN) ? s[i] : 0.f);
                }
                *(bf16x8*)&Bs[row][c + h * 8] = pk;
            }
        }
        __syncthreads();
        bf16x8 a = *(const bf16x8*)&As[w * 16 + cl][lh * 8];
#pragma unroll
        for (int nt = 0; nt < 16; ++nt) {
            bf16x8 b = *(const bf16x8*)&Bs[nt * 16 + cl][lh * 8];
            acc[nt] = mfma16(a, b, acc[nt]);
        }
        __syncthreads();
    }
#pragma unroll
    for (int nt = 0; nt < 16; ++nt) {
#pragma unroll
        for (int r = 0; r < 4; ++r) {
            int rm  = rm0 + w * 16 + 4 * lh + r;
            int col = n0 + nt * 16 + cl;
            int b = rm >> 7, t = rm & 127;          // X rows are b*128+t
            size_t ro = (size_t)t * BB + b;
            if (col < 512) {
                float v = acc[nt][r] + bih[col] + bhh[col];
                *(fp16*)(gxrz2b + ro * 1024 + (col & 255) * 4 + (col >> 8) * 2) = (fp16)v;
            } else {
                gxn[ro * 256 + (col - 512)] = acc[nt][r] + bih[col];
            }
        }
    }
}

// ---------------------------------------------------------------------------
// Layers 1/2 input GEMM: same epilogue; A = Y bf16 [t*128+b][256].
// ---------------------------------------------------------------------------
__global__ __launch_bounds__(512) void gemm_gxy(const bf16* __restrict__ Y,
                                                const float* __restrict__ W,
                                                const float* __restrict__ bih,
                                                const float* __restrict__ bhh,
                                                char*  __restrict__ gxrz2b,
                                                float* __restrict__ gxn)
{
    __shared__ bf16 As[128][40];
    __shared__ bf16 Bs[256][40];
    const int tid  = threadIdx.x;
    const int lane = tid & 63;
    const int w    = tid >> 6;
    const int cl   = lane & 15;
    const int lh   = lane >> 4;
    const int rm0  = blockIdx.x * 128;
    const int n0   = blockIdx.y * 256;

    f32x4 acc[16];
#pragma unroll
    for (int i = 0; i < 16; ++i) acc[i] = (f32x4){0.f, 0.f, 0.f, 0.f};

    for (int kt = 0; kt < 8; ++kt) {
        const int k0 = kt * 32;
        {
            int row = tid >> 2;
            int c   = (tid & 3) * 8;
            *(bf16x8*)&As[row][c] =
                *(const bf16x8*)(Y + (size_t)(rm0 + row) * 256 + k0 + c);
        }
        {
            int row = tid >> 1;
            int c   = (tid & 1) * 16;
            const float* src = W + (size_t)(n0 + row) * 256 + (k0 + c);
#pragma unroll
            for (int h = 0; h < 2; ++h) {
                const float2* s2 = (const float2*)(src + h * 8);
                float2 v0 = s2[0], v1 = s2[1], v2 = s2[2], v3 = s2[3];
                bf16x8 pk;
                pk[0] = (bf16)v0.x; pk[1] = (bf16)v0.y; pk[2] = (bf16)v1.x; pk[3] = (bf16)v1.y;
                pk[4] = (bf16)v2.x; pk[5] = (bf16)v2.y; pk[6] = (bf16)v3.x; pk[7] = (bf16)v3.y;
                *(bf16x8*)&Bs[row][c + h * 8] = pk;
            }
        }
        __syncthreads();
        bf16x8 a = *(const bf16x8*)&As[w * 16 + cl][lh * 8];
#pragma unroll
        for (int nt = 0; nt < 16; ++nt) {
            bf16x8 b = *(const bf16x8*)&Bs[nt * 16 + cl][lh * 8];
            acc[nt] = mfma16(a, b, acc[nt]);
        }
        __syncthreads();
    }
#pragma unroll
    for (int nt = 0; nt < 16; ++nt) {
#pragma unroll
        for (int r = 0; r < 4; ++r) {
            size_t rm = (size_t)(rm0 + w * 16 + 4 * lh + r);   // = t*128 + b
            int col = n0 + nt * 16 + cl;
            if (col < 512) {
                float v = acc[nt][r] + bih[col] + bhh[col];
                *(fp16*)(gxrz2b + rm * 1024 + (col & 255) * 4 + (col >> 8) * 2) = (fp16)v;
            } else {
                gxn[rm * 256 + (col - 512)] = acc[nt][r] + bih[col];
            }
        }
    }
}

// ---------------------------------------------------------------------------
// Recurrent layer v7 = round-9 structure + amdgpu_waves_per_eu(2,2):
// pins the scheduler's occupancy TARGET at 2 waves/EU (256-VGPR pressure
// limit), so the 48 loop-invariant B-fragments (192 VGPRs) stay resident
// instead of being rematerialized from L2 every timestep.
// ---------------------------------------------------------------------------
__global__ __launch_bounds__(512)
__attribute__((amdgpu_waves_per_eu(2, 2)))
void gru_rec(
    const unsigned int* __restrict__ grzp,  // [T*B][256] dwords: (fp16 r, fp16 z)
    const float* __restrict__ gxn,          // [T*B][256] fp32 (n, incl b_ih)
    const bf16*  __restrict__ Wh,           // this layer's hh pack
    const float* __restrict__ bhh,          // raw b_hh (768); only n-part used
    const float* __restrict__ h0,           // hidden + l*128*256
    bf16*  __restrict__ Y,                  // [T*B][256] bf16 out
    float* __restrict__ hnfL)               // hnf + l*256 (stride 768)
{
    __shared__ bf16 Ah[16][264];
    __shared__ __align__(16) char gxl[2][2][16][1040];  // [slot][rz|n][row][1KB+16 pad]

    const int tid  = threadIdx.x;
    const int lane = tid & 63;
    const int w    = tid >> 6;              // 0..7
    const int cl   = lane & 15;
    const int lh   = lane >> 4;
    const int g    = blockIdx.x;

    // ---- 48 B-fragments -> registers ----
    bf16x8 Br[2][8], Bz[2][8], Bn[2][8];
#pragma unroll
    for (int ji = 0; ji < 2; ++ji) {
        const int jt = 2 * w + ji;
#pragma unroll
        for (int kk = 0; kk < 8; ++kk) {
            Br[ji][kk] = *(const bf16x8*)(Wh + (size_t)(( jt       * 8 + kk) * 512) + lane * 8);
            Bz[ji][kk] = *(const bf16x8*)(Wh + (size_t)(((16 + jt) * 8 + kk) * 512) + lane * 8);
            Bn[ji][kk] = *(const bf16x8*)(Wh + (size_t)(((32 + jt) * 8 + kk) * 512) + lane * 8);
        }
    }
    float bN[2];
#pragma unroll
    for (int ji = 0; ji < 2; ++ji)
        bN[ji] = bhh[512 + (2 * w + ji) * 16 + cl];

    // gx tile stage: wave w stages rows {2w, 2w+1} of both planes (DMA, 16B/lane)
    auto STAGE = [&](int tt, int slot) {
#pragma unroll
        for (int i = 0; i < 2; ++i) {
            const int row = 2 * w + i;
            const size_t gr = (size_t)tt * BB + g * 16 + row;
            const unsigned int* s0 = grzp + gr * 256 + lane * 4;
            const float*        s1 = gxn  + gr * 256 + lane * 4;
            __builtin_amdgcn_global_load_lds(
                (const __attribute__((address_space(1))) void*)s0,
                (__attribute__((address_space(3))) void*)&gxl[slot][0][row][0], 16, 0, 0);
            __builtin_amdgcn_global_load_lds(
                (const __attribute__((address_space(1))) void*)s1,
                (__attribute__((address_space(3))) void*)&gxl[slot][1][row][0], 16, 0, 0);
        }
    };

    // ---- prologue: h0 -> regs + Ah; issue tile 0 ----
    float hprev[2][4];
#pragma unroll
    for (int ji = 0; ji < 2; ++ji) {
        const int col = (2 * w + ji) * 16 + cl;
#pragma unroll
        for (int r = 0; r < 4; ++r) {
            const int m = 4 * lh + r;
            float v = h0[(size_t)(g * 16 + m) * 256 + col];
            hprev[ji][r] = v;
            Ah[m][col] = (bf16)v;
        }
    }
    STAGE(0, 0);
    __syncthreads();   // one-time full drain (tile 0 + Ah staged)

    for (int t = 0; t < TT; ++t) {
        const int slot = t & 1;
        // ---- phase 1: issue next tile, MFMA over Ah ----
        STAGE((t + 1 < TT) ? t + 1 : TT - 1, slot ^ 1);
        f32x4 cr[2], cz[2], cn[2];
#pragma unroll
        for (int i = 0; i < 2; ++i) {
            cr[i] = (f32x4){0.f,0.f,0.f,0.f};
            cz[i] = (f32x4){0.f,0.f,0.f,0.f};
            cn[i] = (f32x4){0.f,0.f,0.f,0.f};
        }
#pragma unroll
        for (int kk = 0; kk < 8; ++kk) {
            bf16x8 a = *(const bf16x8*)&Ah[cl][kk * 32 + lh * 8];
#pragma unroll
            for (int ji = 0; ji < 2; ++ji) {
                cr[ji] = mfma16(a, Br[ji][kk], cr[ji]);
                cz[ji] = mfma16(a, Bz[ji][kk], cz[ji]);
                cn[ji] = mfma16(a, Bn[ji][kk], cn[ji]);
            }
        }
        asm volatile("s_waitcnt lgkmcnt(0)" ::: "memory");
        __builtin_amdgcn_sched_barrier(0);
        __builtin_amdgcn_s_barrier();          // A: all Ah reads done
        __builtin_amdgcn_sched_barrier(0);

        // ---- tile t ready? (newer ops: 1 Y-store + 4 next-tile loads) ----
        if (t == 0) asm volatile("s_waitcnt vmcnt(4)" ::: "memory");
        else        asm volatile("s_waitcnt vmcnt(5)" ::: "memory");
        __builtin_amdgcn_sched_barrier(0);

        // ---- gates: gx from LDS, h update, Ah write ----
#pragma unroll
        for (int ji = 0; ji < 2; ++ji) {
            const int col = (2 * w + ji) * 16 + cl;
#pragma unroll
            for (int r = 0; r < 4; ++r) {
                const int m = 4 * lh + r;
                unsigned int rzu = *(const unsigned int*)&gxl[slot][0][m][col * 4];
                float gnv        = *(const float*)       &gxl[slot][1][m][col * 4];
                fp16x2 rz = __builtin_bit_cast(fp16x2, rzu);
                float rr_ = sigf((float)rz[0] + cr[ji][r]);
                float zz  = sigf((float)rz[1] + cz[ji][r]);
                float nn  = tanhfast(gnv + rr_ * (cn[ji][r] + bN[ji]));
                float hnew = (1.f - zz) * nn + zz * hprev[ji][r];
                hprev[ji][r] = hnew;
                Ah[m][col] = (bf16)hnew;
                if (t == TT - 1) hnfL[(size_t)(g * 16 + m) * 768 + col] = hnew;
            }
        }
        asm volatile("s_waitcnt lgkmcnt(0)" ::: "memory");
        __builtin_amdgcn_sched_barrier(0);
        __builtin_amdgcn_s_barrier();          // B: Ah writes visible
        __builtin_amdgcn_sched_barrier(0);

        // ---- vectorized Y epilogue (store stays in flight) ----
        {
            const int yrow = tid >> 5;          // 0..15
            const int yc   = (tid & 31) * 8;    // 0..248
            bf16x8 yv = *(const bf16x8*)&Ah[yrow][yc];
            *(bf16x8*)(Y + ((size_t)t * BB + g * 16 + yrow) * 256 + yc) = yv;
        }
    }
}

// ---------------------------------------------------------------------------
__global__ __launch_bounds__(256) void fc_out(const float* __restrict__ hn,
                                              const float* __restrict__ fcw,
                                              const float* __restrict__ fcb,
                                              float* __restrict__ out)
{
    __shared__ float hs[768];
    const int b = blockIdx.x;
    for (int i = threadIdx.x; i < 768; i += 256) hs[i] = hn[(size_t)b * 768 + i];
    __syncthreads();
    for (int i = threadIdx.x; i < H_IN; i += 256) {
        const float4* wr = (const float4*)(fcw + (size_t)i * 768);
        float a0 = 0.f, a1 = 0.f, a2 = 0.f, a3 = 0.f;
#pragma unroll 4
        for (int c = 0; c < 192; ++c) {
            float4 wv = wr[c];
            const float* h4 = &hs[c * 4];
            a0 += wv.x * h4[0]; a1 += wv.y * h4[1];
            a2 += wv.z * h4[2]; a3 += wv.w * h4[3];
        }
        out[(size_t)b * H_IN + i] = fcb[i] + a0 + a1 + a2 + a3;
    }
}

extern "C" void kernel_launch(void* const* d_in, const int* in_sizes, int n_in,
                              void* d_out, int out_size, void* d_ws, size_t ws_size,
                              hipStream_t stream) {
    const float* X    = (const float*)d_in[0];
    const float* hid  = (const float*)d_in[1];
    const float* wih0 = (const float*)d_in[2];
    const float* whh0 = (const float*)d_in[3];
    const float* bih0 = (const float*)d_in[4];
    const float* bhh0 = (const float*)d_in[5];
    const float* wih1 = (const float*)d_in[6];
    const float* whh1 = (const float*)d_in[7];
    const float* bih1 = (const float*)d_in[8];
    const float* bhh1 = (const float*)d_in[9];
    const float* wih2 = (const float*)d_in[10];
    const float* whh2 = (const float*)d_in[11];
    const float* bih2 = (const float*)d_in[12];
    const float* bhh2 = (const float*)d_in[13];
    const float* fcw  = (const float*)d_in[14];
    const float* fcb  = (const float*)d_in[15];
    float* out = (float*)d_out;

    // Layout (total 43,525,120 B — within the known-safe 52.7 MB):
    char* ws = (char*)d_ws;
    bf16*  Wh    = (bf16*)ws;                      //          0 .. 1,179,648
    float* hnf   = (float*)(ws + 1188864);         //  1,188,864 .. 1,582,080
    bf16*  Y     = (bf16*)(ws + 1582080);          //  1,582,080 .. 9,970,688
    float* gxn   = (float*)(ws + 9970688);         //  9,970,688 .. 26,747,904
    char*  gxrzb = ws + 26747904;                  // 26,747,904 .. 43,525,120
    const unsigned int* grzp = (const unsigned int*)gxrzb;

    prep_pack2<<<dim3(1152), dim3(512), 0, stream>>>(whh0, whh1, whh2, Wh);
    // layer 0
    gemm_gx0<<<dim3(128, 3), dim3(512), 0, stream>>>(X, wih0, bih0, bhh0, gxrzb, gxn);
    gru_rec<<<dim3(8), dim3(512), 0, stream>>>(grzp, gxn, Wh, bhh0,
                                               hid, Y, hnf);
    // layer 1
    gemm_gxy<<<dim3(128, 3), dim3(512), 0, stream>>>(Y, wih1, bih1, bhh1, gxrzb, gxn);
    gru_rec<<<dim3(8), dim3(512), 0, stream>>>(grzp, gxn, Wh + 196608, bhh1,
                                               hid + 32768, Y, hnf + 256);
    // layer 2
    gemm_gxy<<<dim3(128, 3), dim3(512), 0, stream>>>(Y, wih2, bih2, bhh2, gxrzb, gxn);
    gru_rec<<<dim3(8), dim3(512), 0, stream>>>(grzp, gxn, Wh + 393216, bhh2,
                                               hid + 65536, Y, hnf + 512);
    // head
    fc_out<<<dim3(128), dim3(256), 0, stream>>>(hnf, fcw, fcb, out);
    hipMemcpyAsync(out + 171776, hid, 98304 * sizeof(float),
                   hipMemcpyDeviceToDevice, stream);
}

// Round 13
// 1759.743 us; speedup vs baseline: 1.4524x; 1.0259x over previous
//
#include <hip/hip_runtime.h>
#include <hip/hip_bf16.h>

typedef __bf16 bf16;
typedef _Float16 fp16;
typedef __attribute__((ext_vector_type(8))) __bf16 bf16x8;
typedef __attribute__((ext_vector_type(2))) _Float16 fp16x2;
typedef __attribute__((ext_vector_type(4))) float f32x4;

#define H_IN 1342
#define TT   128
#define BB   128

static __device__ __forceinline__ f32x4 mfma16(bf16x8 a, bf16x8 b, f32x4 c) {
    return __builtin_amdgcn_mfma_f32_16x16x32_bf16(a, b, c, 0, 0, 0);
}
// MFMA with AGPR-resident B operand: the "a" constraint forces the weight
// fragment to live in the accumulator file across the whole t-loop; loads
// cannot target AGPRs and two-instruction chains are not rematerialized,
// so the compiler cannot re-stream the weights from L2 inside the loop.
static __device__ __forceinline__ void mfma_a(f32x4& c, const bf16x8& a, const bf16x8& b) {
    asm volatile("v_mfma_f32_16x16x32_bf16 %0, %1, %2, %0"
                 : "+v"(c)
                 : "v"(a), "a"(b));
}
static __device__ __forceinline__ float sigf(float x) {
    return 1.f / (1.f + __expf(-x));
}
static __device__ __forceinline__ float tanhfast(float x) {
    return 2.f / (1.f + __expf(-2.f * x)) - 1.f;
}

// ---------------------------------------------------------------------------
// Pack the three w_hh matrices (768x256) into MFMA B-fragment order.
// (round-6 verified)
// ---------------------------------------------------------------------------
__global__ void prep_pack2(const float* __restrict__ whh0,
                           const float* __restrict__ whh1,
                           const float* __restrict__ whh2,
                           bf16* __restrict__ Wh)
{
    int idx = blockIdx.x * blockDim.x + threadIdx.x;
    if (idx < 589824) {
        int l = idx / 196608;
        int r = idx - l * 196608;
        const float* w = (l == 0) ? whh0 : (l == 1) ? whh1 : whh2;
        int f = r >> 9, q = r & 511;
        int lane = q >> 3, j = q & 7;
        int nt = f >> 3, kt = f & 7;
        int n = nt * 16 + (lane & 15);
        int k = kt * 32 + (lane >> 4) * 8 + j;
        Wh[idx] = (bf16)w[n * 256 + k];
    }
}

// ---------------------------------------------------------------------------
// Layer-0 input GEMM. Epilogue: r,z -> interleaved fp16x2 dword plane
// (lo=r, hi=z, b_hh folded), n -> fp32 plane. (round-6..12 verified)
// ---------------------------------------------------------------------------
__global__ __launch_bounds__(512) void gemm_gx0(const float* __restrict__ X,
                                                const float* __restrict__ W,
                                                const float* __restrict__ bih,
                                                const float* __restrict__ bhh,
                                                char*  __restrict__ gxrz2b,
                                                float* __restrict__ gxn)
{
    __shared__ bf16 As[128][40];
    __shared__ bf16 Bs[256][40];
    const int tid  = threadIdx.x;
    const int lane = tid & 63;
    const int w    = tid >> 6;
    const int cl   = lane & 15;
    const int lh   = lane >> 4;
    const int rm0  = blockIdx.x * 128;
    const int n0   = blockIdx.y * 256;

    f32x4 acc[16];
#pragma unroll
    for (int i = 0; i < 16; ++i) acc[i] = (f32x4){0.f, 0.f, 0.f, 0.f};

    for (int kt = 0; kt < 42; ++kt) {
        const int k0 = kt * 32;
        {
            int row = tid >> 2;
            int c   = (tid & 3) * 8;
            const float* src = X + (size_t)(rm0 + row) * H_IN + (k0 + c);
            bf16x8 pk;
            if (k0 + c + 8 <= H_IN) {
                const float2* s2 = (const float2*)src;
                float2 v0 = s2[0], v1 = s2[1], v2 = s2[2], v3 = s2[3];
                pk[0] = (bf16)v0.x; pk[1] = (bf16)v0.y; pk[2] = (bf16)v1.x; pk[3] = (bf16)v1.y;
                pk[4] = (bf16)v2.x; pk[5] = (bf16)v2.y; pk[6] = (bf16)v3.x; pk[7] = (bf16)v3.y;
            } else {
#pragma unroll
                for (int i = 0; i < 8; ++i)
                    pk[i] = (bf16)((k0 + c + i < H_IN) ? src[i] : 0.f);
            }
            *(bf16x8*)&As[row][c] = pk;
        }
        {
            int row = tid >> 1;
            int c   = (tid & 1) * 16;
            const float* src = W + (size_t)(n0 + row) * H_IN + (k0 + c);
#pragma unroll
            for (int h = 0; h < 2; ++h) {
                const float* s = src + h * 8;
                bf16x8 pk;
                if (k0 + c + h * 8 + 8 <= H_IN) {
                    const float2* s2 = (const float2*)s;
                    float2 v0 = s2[0], v1 = s2[1], v2 = s2[2], v3 = s2[3];
                    pk[0] = (bf16)v0.x; pk[1] = (bf16)v0.y; pk[2] = (bf16)v1.x; pk[3] = (bf16)v1.y;
                    pk[4] = (bf16)v2.x; pk[5] = (bf16)v2.y; pk[6] = (bf16)v3.x; pk[7] = (bf16)v3.y;
                } else {
#pragma unroll
                    for (int i = 0; i < 8; ++i)
                        pk[i] = (bf16)((k0 + c + h * 8 + i < H_IN) ? s[i] : 0.f);
                }
                *(bf16x8*)&Bs[row][c + h * 8] = pk;
            }
        }
        __syncthreads();
        bf16x8 a = *(const bf16x8*)&As[w * 16 + cl][lh * 8];
#pragma unroll
        for (int nt = 0; nt < 16; ++nt) {
            bf16x8 b = *(const bf16x8*)&Bs[nt * 16 + cl][lh * 8];
            acc[nt] = mfma16(a, b, acc[nt]);
        }
        __syncthreads();
    }
#pragma unroll
    for (int nt = 0; nt < 16; ++nt) {
#pragma unroll
        for (int r = 0; r < 4; ++r) {
            int rm  = rm0 + w * 16 + 4 * lh + r;
            int col = n0 + nt * 16 + cl;
            int b = rm >> 7, t = rm & 127;          // X rows are b*128+t
            size_t ro = (size_t)t * BB + b;
            if (col < 512) {
                float v = acc[nt][r] + bih[col] + bhh[col];
                *(fp16*)(gxrz2b + ro * 1024 + (col & 255) * 4 + (col >> 8) * 2) = (fp16)v;
            } else {
                gxn[ro * 256 + (col - 512)] = acc[nt][r] + bih[col];
            }
        }
    }
}

// ---------------------------------------------------------------------------
// Layers 1/2 input GEMM: same epilogue; A = Y bf16 [t*128+b][256].
// ---------------------------------------------------------------------------
__global__ __launch_bounds__(512) void gemm_gxy(const bf16* __restrict__ Y,
                                                const float* __restrict__ W,
                                                const float* __restrict__ bih,
                                                const float* __restrict__ bhh,
                                                char*  __restrict__ gxrz2b,
                                                float* __restrict__ gxn)
{
    __shared__ bf16 As[128][40];
    __shared__ bf16 Bs[256][40];
    const int tid  = threadIdx.x;
    const int lane = tid & 63;
    const int w    = tid >> 6;
    const int cl   = lane & 15;
    const int lh   = lane >> 4;
    const int rm0  = blockIdx.x * 128;
    const int n0   = blockIdx.y * 256;

    f32x4 acc[16];
#pragma unroll
    for (int i = 0; i < 16; ++i) acc[i] = (f32x4){0.f, 0.f, 0.f, 0.f};

    for (int kt = 0; kt < 8; ++kt) {
        const int k0 = kt * 32;
        {
            int row = tid >> 2;
            int c   = (tid & 3) * 8;
            *(bf16x8*)&As[row][c] =
                *(const bf16x8*)(Y + (size_t)(rm0 + row) * 256 + k0 + c);
        }
        {
            int row = tid >> 1;
            int c   = (tid & 1) * 16;
            const float* src = W + (size_t)(n0 + row) * 256 + (k0 + c);
#pragma unroll
            for (int h = 0; h < 2; ++h) {
                const float2* s2 = (const float2*)(src + h * 8);
                float2 v0 = s2[0], v1 = s2[1], v2 = s2[2], v3 = s2[3];
                bf16x8 pk;
                pk[0] = (bf16)v0.x; pk[1] = (bf16)v0.y; pk[2] = (bf16)v1.x; pk[3] = (bf16)v1.y;
                pk[4] = (bf16)v2.x; pk[5] = (bf16)v2.y; pk[6] = (bf16)v3.x; pk[7] = (bf16)v3.y;
                *(bf16x8*)&Bs[row][c + h * 8] = pk;
            }
        }
        __syncthreads();
        bf16x8 a = *(const bf16x8*)&As[w * 16 + cl][lh * 8];
#pragma unroll
        for (int nt = 0; nt < 16; ++nt) {
            bf16x8 b = *(const bf16x8*)&Bs[nt * 16 + cl][lh * 8];
            acc[nt] = mfma16(a, b, acc[nt]);
        }
        __syncthreads();
    }
#pragma unroll
    for (int nt = 0; nt < 16; ++nt) {
#pragma unroll
        for (int r = 0; r < 4; ++r) {
            size_t rm = (size_t)(rm0 + w * 16 + 4 * lh + r);   // = t*128 + b
            int col = n0 + nt * 16 + cl;
            if (col < 512) {
                float v = acc[nt][r] + bih[col] + bhh[col];
                *(fp16*)(gxrz2b + rm * 1024 + (col & 255) * 4 + (col >> 8) * 2) = (fp16)v;
            } else {
                gxn[rm * 256 + (col - 512)] = acc[nt][r] + bih[col];
            }
        }
    }
}

// ---------------------------------------------------------------------------
// Recurrent layer v8 = round-9 structure, but MFMA via inline asm with the
// B operand constrained to AGPRs ("a") — weights live in the accumulator
// file for the whole t-loop (192 AGPR + <=64 arch VGPR at 2 waves/SIMD).
// ---------------------------------------------------------------------------
__global__ __launch_bounds__(512)
void gru_rec(
    const unsigned int* __restrict__ grzp,  // [T*B][256] dwords: (fp16 r, fp16 z)
    const float* __restrict__ gxn,          // [T*B][256] fp32 (n, incl b_ih)
    const bf16*  __restrict__ Wh,           // this layer's hh pack
    const float* __restrict__ bhh,          // raw b_hh (768); only n-part used
    const float* __restrict__ h0,           // hidden + l*128*256
    bf16*  __restrict__ Y,                  // [T*B][256] bf16 out
    float* __restrict__ hnfL)               // hnf + l*256 (stride 768)
{
    __shared__ bf16 Ah[16][264];
    __shared__ __align__(16) char gxl[2][2][16][1040];  // [slot][rz|n][row][1KB+16 pad]

    const int tid  = threadIdx.x;
    const int lane = tid & 63;
    const int w    = tid >> 6;              // 0..7
    const int cl   = lane & 15;
    const int lh   = lane >> 4;
    const int g    = blockIdx.x;

    // ---- 48 B-fragments -> AGPR-homed values (all uses are "a"-constrained) ----
    bf16x8 Br[2][8], Bz[2][8], Bn[2][8];
#pragma unroll
    for (int ji = 0; ji < 2; ++ji) {
        const int jt = 2 * w + ji;
#pragma unroll
        for (int kk = 0; kk < 8; ++kk) {
            Br[ji][kk] = *(const bf16x8*)(Wh + (size_t)(( jt       * 8 + kk) * 512) + lane * 8);
            Bz[ji][kk] = *(const bf16x8*)(Wh + (size_t)(((16 + jt) * 8 + kk) * 512) + lane * 8);
            Bn[ji][kk] = *(const bf16x8*)(Wh + (size_t)(((32 + jt) * 8 + kk) * 512) + lane * 8);
        }
    }
    float bN[2];
#pragma unroll
    for (int ji = 0; ji < 2; ++ji)
        bN[ji] = bhh[512 + (2 * w + ji) * 16 + cl];

    // gx tile stage: wave w stages rows {2w, 2w+1} of both planes (DMA, 16B/lane)
    auto STAGE = [&](int tt, int slot) {
#pragma unroll
        for (int i = 0; i < 2; ++i) {
            const int row = 2 * w + i;
            const size_t gr = (size_t)tt * BB + g * 16 + row;
            const unsigned int* s0 = grzp + gr * 256 + lane * 4;
            const float*        s1 = gxn  + gr * 256 + lane * 4;
            __builtin_amdgcn_global_load_lds(
                (const __attribute__((address_space(1))) void*)s0,
                (__attribute__((address_space(3))) void*)&gxl[slot][0][row][0], 16, 0, 0);
            __builtin_amdgcn_global_load_lds(
                (const __attribute__((address_space(1))) void*)s1,
                (__attribute__((address_space(3))) void*)&gxl[slot][1][row][0], 16, 0, 0);
        }
    };

    // ---- prologue: h0 -> regs + Ah; issue tile 0 ----
    float hprev[2][4];
#pragma unroll
    for (int ji = 0; ji < 2; ++ji) {
        const int col = (2 * w + ji) * 16 + cl;
#pragma unroll
        for (int r = 0; r < 4; ++r) {
            const int m = 4 * lh + r;
            float v = h0[(size_t)(g * 16 + m) * 256 + col];
            hprev[ji][r] = v;
            Ah[m][col] = (bf16)v;
        }
    }
    STAGE(0, 0);
    __syncthreads();   // one-time full drain (tile 0 + Ah staged)

    for (int t = 0; t < TT; ++t) {
        const int slot = t & 1;
        // ---- phase 1: issue next tile, MFMA over Ah ----
        STAGE((t + 1 < TT) ? t + 1 : TT - 1, slot ^ 1);
        f32x4 cr[2], cz[2], cn[2];
#pragma unroll
        for (int i = 0; i < 2; ++i) {
            cr[i] = (f32x4){0.f,0.f,0.f,0.f};
            cz[i] = (f32x4){0.f,0.f,0.f,0.f};
            cn[i] = (f32x4){0.f,0.f,0.f,0.f};
        }
#pragma unroll
        for (int kk = 0; kk < 8; ++kk) {
            bf16x8 a = *(const bf16x8*)&Ah[cl][kk * 32 + lh * 8];
#pragma unroll
            for (int ji = 0; ji < 2; ++ji) {
                mfma_a(cr[ji], a, Br[ji][kk]);
                mfma_a(cz[ji], a, Bz[ji][kk]);
                mfma_a(cn[ji], a, Bn[ji][kk]);
            }
        }
        asm volatile("s_waitcnt lgkmcnt(0)" ::: "memory");
        __builtin_amdgcn_sched_barrier(0);
        __builtin_amdgcn_s_barrier();          // A: all Ah reads done
        __builtin_amdgcn_sched_barrier(0);

        // ---- tile t ready? (newer ops: 1 Y-store + 4 next-tile loads) ----
        if (t == 0) asm volatile("s_waitcnt vmcnt(4)" ::: "memory");
        else        asm volatile("s_waitcnt vmcnt(5)" ::: "memory");
        __builtin_amdgcn_sched_barrier(0);

        // ---- gates: gx from LDS, h update, Ah write ----
#pragma unroll
        for (int ji = 0; ji < 2; ++ji) {
            const int col = (2 * w + ji) * 16 + cl;
#pragma unroll
            for (int r = 0; r < 4; ++r) {
                const int m = 4 * lh + r;
                unsigned int rzu = *(const unsigned int*)&gxl[slot][0][m][col * 4];
                float gnv        = *(const float*)       &gxl[slot][1][m][col * 4];
                fp16x2 rz = __builtin_bit_cast(fp16x2, rzu);
                float rr_ = sigf((float)rz[0] + cr[ji][r]);
                float zz  = sigf((float)rz[1] + cz[ji][r]);
                float nn  = tanhfast(gnv + rr_ * (cn[ji][r] + bN[ji]));
                float hnew = (1.f - zz) * nn + zz * hprev[ji][r];
                hprev[ji][r] = hnew;
                Ah[m][col] = (bf16)hnew;
                if (t == TT - 1) hnfL[(size_t)(g * 16 + m) * 768 + col] = hnew;
            }
        }
        asm volatile("s_waitcnt lgkmcnt(0)" ::: "memory");
        __builtin_amdgcn_sched_barrier(0);
        __builtin_amdgcn_s_barrier();          // B: Ah writes visible
        __builtin_amdgcn_sched_barrier(0);

        // ---- vectorized Y epilogue (store stays in flight) ----
        {
            const int yrow = tid >> 5;          // 0..15
            const int yc   = (tid & 31) * 8;    // 0..248
            bf16x8 yv = *(const bf16x8*)&Ah[yrow][yc];
            *(bf16x8*)(Y + ((size_t)t * BB + g * 16 + yrow) * 256 + yc) = yv;
        }
    }
}

// ---------------------------------------------------------------------------
__global__ __launch_bounds__(256) void fc_out(const float* __restrict__ hn,
                                              const float* __restrict__ fcw,
                                              const float* __restrict__ fcb,
                                              float* __restrict__ out)
{
    __shared__ float hs[768];
    const int b = blockIdx.x;
    for (int i = threadIdx.x; i < 768; i += 256) hs[i] = hn[(size_t)b * 768 + i];
    __syncthreads();
    for (int i = threadIdx.x; i < H_IN; i += 256) {
        const float4* wr = (const float4*)(fcw + (size_t)i * 768);
        float a0 = 0.f, a1 = 0.f, a2 = 0.f, a3 = 0.f;
#pragma unroll 4
        for (int c = 0; c < 192; ++c) {
            float4 wv = wr[c];
            const float* h4 = &hs[c * 4];
            a0 += wv.x * h4[0]; a1 += wv.y * h4[1];
            a2 += wv.z * h4[2]; a3 += wv.w * h4[3];
        }
        out[(size_t)b * H_IN + i] = fcb[i] + a0 + a1 + a2 + a3;
    }
}

extern "C" void kernel_launch(void* const* d_in, const int* in_sizes, int n_in,
                              void* d_out, int out_size, void* d_ws, size_t ws_size,
                              hipStream_t stream) {
    const float* X    = (const float*)d_in[0];
    const float* hid  = (const float*)d_in[1];
    const float* wih0 = (const float*)d_in[2];
    const float* whh0 = (const float*)d_in[3];
    const float* bih0 = (const float*)d_in[4];
    const float* bhh0 = (const float*)d_in[5];
    const float* wih1 = (const float*)d_in[6];
    const float* whh1 = (const float*)d_in[7];
    const float* bih1 = (const float*)d_in[8];
    const float* bhh1 = (const float*)d_in[9];
    const float* wih2 = (const float*)d_in[10];
    const float* whh2 = (const float*)d_in[11];
    const float* bih2 = (const float*)d_in[12];
    const float* bhh2 = (const float*)d_in[13];
    const float* fcw  = (const float*)d_in[14];
    const float* fcb  = (const float*)d_in[15];
    float* out = (float*)d_out;

    // Layout (total 43,525,120 B — within the known-safe 52.7 MB):
    char* ws = (char*)d_ws;
    bf16*  Wh    = (bf16*)ws;                      //          0 .. 1,179,648
    float* hnf   = (float*)(ws + 1188864);         //  1,188,864 .. 1,582,080
    bf16*  Y     = (bf16*)(ws + 1582080);          //  1,582,080 .. 9,970,688
    float* gxn   = (float*)(ws + 9970688);         //  9,970,688 .. 26,747,904
    char*  gxrzb = ws + 26747904;                  // 26,747,904 .. 43,525,120
    const unsigned int* grzp = (const unsigned int*)gxrzb;

    prep_pack2<<<dim3(1152), dim3(512), 0, stream>>>(whh0, whh1, whh2, Wh);
    // layer 0
    gemm_gx0<<<dim3(128, 3), dim3(512), 0, stream>>>(X, wih0, bih0, bhh0, gxrzb, gxn);
    gru_rec<<<dim3(8), dim3(512), 0, stream>>>(grzp, gxn, Wh, bhh0,
                                               hid, Y, hnf);
    // layer 1
    gemm_gxy<<<dim3(128, 3), dim3(512), 0, stream>>>(Y, wih1, bih1, bhh1, gxrzb, gxn);
    gru_rec<<<dim3(8), dim3(512), 0, stream>>>(grzp, gxn, Wh + 196608, bhh1,
                                               hid + 32768, Y, hnf + 256);
    // layer 2
    gemm_gxy<<<dim3(128, 3), dim3(512), 0, stream>>>(Y, wih2, bih2, bhh2, gxrzb, gxn);
    gru_rec<<<dim3(8), dim3(512), 0, stream>>>(grzp, gxn, Wh + 393216, bhh2,
                                               hid + 65536, Y, hnf + 512);
    // head
    fc_out<<<dim3(128), dim3(256), 0, stream>>>(hnf, fcw, fcb, out);
    hipMemcpyAsync(out + 171776, hid, 98304 * sizeof(float),
                   hipMemcpyDeviceToDevice, stream);
}

// Round 14
// 1753.000 us; speedup vs baseline: 1.4579x; 1.0038x over previous
//
#include <hip/hip_runtime.h>
#include <hip/hip_bf16.h>

typedef __bf16 bf16;
typedef _Float16 fp16;
typedef __attribute__((ext_vector_type(8))) __bf16 bf16x8;
typedef __attribute__((ext_vector_type(2))) _Float16 fp16x2;
typedef __attribute__((ext_vector_type(4))) float f32x4;

#define H_IN 1342
#define TT   128
#define BB   128

static __device__ __forceinline__ f32x4 mfma16(bf16x8 a, bf16x8 b, f32x4 c) {
    return __builtin_amdgcn_mfma_f32_16x16x32_bf16(a, b, c, 0, 0, 0);
}
static __device__ __forceinline__ float sigf(float x) {
    return 1.f / (1.f + __expf(-x));
}
static __device__ __forceinline__ float tanhfast(float x) {
    return 2.f / (1.f + __expf(-2.f * x)) - 1.f;
}

// ---------------------------------------------------------------------------
// Pack the three w_hh matrices (768x256) into MFMA B-fragment order.
// (round-6 verified)
// ---------------------------------------------------------------------------
__global__ void prep_pack2(const float* __restrict__ whh0,
                           const float* __restrict__ whh1,
                           const float* __restrict__ whh2,
                           bf16* __restrict__ Wh)
{
    int idx = blockIdx.x * blockDim.x + threadIdx.x;
    if (idx < 589824) {
        int l = idx / 196608;
        int r = idx - l * 196608;
        const float* w = (l == 0) ? whh0 : (l == 1) ? whh1 : whh2;
        int f = r >> 9, q = r & 511;
        int lane = q >> 3, j = q & 7;
        int nt = f >> 3, kt = f & 7;
        int n = nt * 16 + (lane & 15);
        int k = kt * 32 + (lane >> 4) * 8 + j;
        Wh[idx] = (bf16)w[n * 256 + k];
    }
}

// ---------------------------------------------------------------------------
// Layer-0 input GEMM. Epilogue: r,z -> interleaved fp16x2 dword plane
// (lo=r, hi=z, b_hh folded), n -> fp32 plane. (round-6..13 verified)
// ---------------------------------------------------------------------------
__global__ __launch_bounds__(512) void gemm_gx0(const float* __restrict__ X,
                                                const float* __restrict__ W,
                                                const float* __restrict__ bih,
                                                const float* __restrict__ bhh,
                                                char*  __restrict__ gxrz2b,
                                                float* __restrict__ gxn)
{
    __shared__ bf16 As[128][40];
    __shared__ bf16 Bs[256][40];
    const int tid  = threadIdx.x;
    const int lane = tid & 63;
    const int w    = tid >> 6;
    const int cl   = lane & 15;
    const int lh   = lane >> 4;
    const int rm0  = blockIdx.x * 128;
    const int n0   = blockIdx.y * 256;

    f32x4 acc[16];
#pragma unroll
    for (int i = 0; i < 16; ++i) acc[i] = (f32x4){0.f, 0.f, 0.f, 0.f};

    for (int kt = 0; kt < 42; ++kt) {
        const int k0 = kt * 32;
        {
            int row = tid >> 2;
            int c   = (tid & 3) * 8;
            const float* src = X + (size_t)(rm0 + row) * H_IN + (k0 + c);
            bf16x8 pk;
            if (k0 + c + 8 <= H_IN) {
                const float2* s2 = (const float2*)src;
                float2 v0 = s2[0], v1 = s2[1], v2 = s2[2], v3 = s2[3];
                pk[0] = (bf16)v0.x; pk[1] = (bf16)v0.y; pk[2] = (bf16)v1.x; pk[3] = (bf16)v1.y;
                pk[4] = (bf16)v2.x; pk[5] = (bf16)v2.y; pk[6] = (bf16)v3.x; pk[7] = (bf16)v3.y;
            } else {
#pragma unroll
                for (int i = 0; i < 8; ++i)
                    pk[i] = (bf16)((k0 + c + i < H_IN) ? src[i] : 0.f);
            }
            *(bf16x8*)&As[row][c] = pk;
        }
        {
            int row = tid >> 1;
            int c   = (tid & 1) * 16;
            const float* src = W + (size_t)(n0 + row) * H_IN + (k0 + c);
#pragma unroll
            for (int h = 0; h < 2; ++h) {
                const float* s = src + h * 8;
                bf16x8 pk;
                if (k0 + c + h * 8 + 8 <= H_IN) {
                    const float2* s2 = (const float2*)s;
                    float2 v0 = s2[0], v1 = s2[1], v2 = s2[2], v3 = s2[3];
                    pk[0] = (bf16)v0.x; pk[1] = (bf16)v0.y; pk[2] = (bf16)v1.x; pk[3] = (bf16)v1.y;
                    pk[4] = (bf16)v2.x; pk[5] = (bf16)v2.y; pk[6] = (bf16)v3.x; pk[7] = (bf16)v3.y;
                } else {
#pragma unroll
                    for (int i = 0; i < 8; ++i)
                        pk[i] = (bf16)((k0 + c + h * 8 + i < H_IN) ? s[i] : 0.f);
                }
                *(bf16x8*)&Bs[row][c + h * 8] = pk;
            }
        }
        __syncthreads();
        bf16x8 a = *(const bf16x8*)&As[w * 16 + cl][lh * 8];
#pragma unroll
        for (int nt = 0; nt < 16; ++nt) {
            bf16x8 b = *(const bf16x8*)&Bs[nt * 16 + cl][lh * 8];
            acc[nt] = mfma16(a, b, acc[nt]);
        }
        __syncthreads();
    }
#pragma unroll
    for (int nt = 0; nt < 16; ++nt) {
#pragma unroll
        for (int r = 0; r < 4; ++r) {
            int rm  = rm0 + w * 16 + 4 * lh + r;
            int col = n0 + nt * 16 + cl;
            int b = rm >> 7, t = rm & 127;          // X rows are b*128+t
            size_t ro = (size_t)t * BB + b;
            if (col < 512) {
                float v = acc[nt][r] + bih[col] + bhh[col];
                *(fp16*)(gxrz2b + ro * 1024 + (col & 255) * 4 + (col >> 8) * 2) = (fp16)v;
            } else {
                gxn[ro * 256 + (col - 512)] = acc[nt][r] + bih[col];
            }
        }
    }
}

// ---------------------------------------------------------------------------
// Layers 1/2 input GEMM: same epilogue; A = Y bf16 [t*128+b][256].
// ---------------------------------------------------------------------------
__global__ __launch_bounds__(512) void gemm_gxy(const bf16* __restrict__ Y,
                                                const float* __restrict__ W,
                                                const float* __restrict__ bih,
                                                const float* __restrict__ bhh,
                                                char*  __restrict__ gxrz2b,
                                                float* __restrict__ gxn)
{
    __shared__ bf16 As[128][40];
    __shared__ bf16 Bs[256][40];
    const int tid  = threadIdx.x;
    const int lane = tid & 63;
    const int w    = tid >> 6;
    const int cl   = lane & 15;
    const int lh   = lane >> 4;
    const int rm0  = blockIdx.x * 128;
    const int n0   = blockIdx.y * 256;

    f32x4 acc[16];
#pragma unroll
    for (int i = 0; i < 16; ++i) acc[i] = (f32x4){0.f, 0.f, 0.f, 0.f};

    for (int kt = 0; kt < 8; ++kt) {
        const int k0 = kt * 32;
        {
            int row = tid >> 2;
            int c   = (tid & 3) * 8;
            *(bf16x8*)&As[row][c] =
                *(const bf16x8*)(Y + (size_t)(rm0 + row) * 256 + k0 + c);
        }
        {
            int row = tid >> 1;
            int c   = (tid & 1) * 16;
            const float* src = W + (size_t)(n0 + row) * 256 + (k0 + c);
#pragma unroll
            for (int h = 0; h < 2; ++h) {
                const float2* s2 = (const float2*)(src + h * 8);
                float2 v0 = s2[0], v1 = s2[1], v2 = s2[2], v3 = s2[3];
                bf16x8 pk;
                pk[0] = (bf16)v0.x; pk[1] = (bf16)v0.y; pk[2] = (bf16)v1.x; pk[3] = (bf16)v1.y;
                pk[4] = (bf16)v2.x; pk[5] = (bf16)v2.y; pk[6] = (bf16)v3.x; pk[7] = (bf16)v3.y;
                *(bf16x8*)&Bs[row][c + h * 8] = pk;
            }
        }
        __syncthreads();
        bf16x8 a = *(const bf16x8*)&As[w * 16 + cl][lh * 8];
#pragma unroll
        for (int nt = 0; nt < 16; ++nt) {
            bf16x8 b = *(const bf16x8*)&Bs[nt * 16 + cl][lh * 8];
            acc[nt] = mfma16(a, b, acc[nt]);
        }
        __syncthreads();
    }
#pragma unroll
    for (int nt = 0; nt < 16; ++nt) {
#pragma unroll
        for (int r = 0; r < 4; ++r) {
            size_t rm = (size_t)(rm0 + w * 16 + 4 * lh + r);   // = t*128 + b
            int col = n0 + nt * 16 + cl;
            if (col < 512) {
                float v = acc[nt][r] + bih[col] + bhh[col];
                *(fp16*)(gxrz2b + rm * 1024 + (col & 255) * 4 + (col >> 8) * 2) = (fp16)v;
            } else {
                gxn[rm * 256 + (col - 512)] = acc[nt][r] + bih[col];
            }
        }
    }
}

// ---------------------------------------------------------------------------
// Recurrent layer v9 = round-12 structure (intrinsic MFMA) with LDS padded
// past 81,920 B: the register allocator's occupancy heuristic then sees
// 1 block/CU (8 waves, 2/SIMD) and budgets 256 VGPRs/wave, letting the 48
// loop-invariant B-fragments (192 VGPRs) stay register-resident instead of
// being re-streamed from L2 every timestep. We always run 1 block/CU anyway
// (8 blocks on 256 CUs), so the padding costs nothing.
// ---------------------------------------------------------------------------
#define GXPAD 1552   // pad stride: 2*2*16*1552 + 8448 = 107,776 B > 81,920
__global__ __launch_bounds__(512, 2)
void gru_rec(
    const unsigned int* __restrict__ grzp,  // [T*B][256] dwords: (fp16 r, fp16 z)
    const float* __restrict__ gxn,          // [T*B][256] fp32 (n, incl b_ih)
    const bf16*  __restrict__ Wh,           // this layer's hh pack
    const float* __restrict__ bhh,          // raw b_hh (768); only n-part used
    const float* __restrict__ h0,           // hidden + l*128*256
    bf16*  __restrict__ Y,                  // [T*B][256] bf16 out
    float* __restrict__ hnfL)               // hnf + l*256 (stride 768)
{
    __shared__ bf16 Ah[16][264];
    __shared__ __align__(16) char gxl[2][2][16][GXPAD];  // [slot][rz|n][row][...]

    const int tid  = threadIdx.x;
    const int lane = tid & 63;
    const int w    = tid >> 6;              // 0..7
    const int cl   = lane & 15;
    const int lh   = lane >> 4;
    const int g    = blockIdx.x;

    // ---- 48 B-fragments -> registers ----
    bf16x8 Br[2][8], Bz[2][8], Bn[2][8];
#pragma unroll
    for (int ji = 0; ji < 2; ++ji) {
        const int jt = 2 * w + ji;
#pragma unroll
        for (int kk = 0; kk < 8; ++kk) {
            Br[ji][kk] = *(const bf16x8*)(Wh + (size_t)(( jt       * 8 + kk) * 512) + lane * 8);
            Bz[ji][kk] = *(const bf16x8*)(Wh + (size_t)(((16 + jt) * 8 + kk) * 512) + lane * 8);
            Bn[ji][kk] = *(const bf16x8*)(Wh + (size_t)(((32 + jt) * 8 + kk) * 512) + lane * 8);
        }
    }
    float bN[2];
#pragma unroll
    for (int ji = 0; ji < 2; ++ji)
        bN[ji] = bhh[512 + (2 * w + ji) * 16 + cl];

    // gx tile stage: wave w stages rows {2w, 2w+1} of both planes (DMA, 16B/lane)
    auto STAGE = [&](int tt, int slot) {
#pragma unroll
        for (int i = 0; i < 2; ++i) {
            const int row = 2 * w + i;
            const size_t gr = (size_t)tt * BB + g * 16 + row;
            const unsigned int* s0 = grzp + gr * 256 + lane * 4;
            const float*        s1 = gxn  + gr * 256 + lane * 4;
            __builtin_amdgcn_global_load_lds(
                (const __attribute__((address_space(1))) void*)s0,
                (__attribute__((address_space(3))) void*)&gxl[slot][0][row][0], 16, 0, 0);
            __builtin_amdgcn_global_load_lds(
                (const __attribute__((address_space(1))) void*)s1,
                (__attribute__((address_space(3))) void*)&gxl[slot][1][row][0], 16, 0, 0);
        }
    };

    // ---- prologue: h0 -> regs + Ah; issue tile 0 ----
    float hprev[2][4];
#pragma unroll
    for (int ji = 0; ji < 2; ++ji) {
        const int col = (2 * w + ji) * 16 + cl;
#pragma unroll
        for (int r = 0; r < 4; ++r) {
            const int m = 4 * lh + r;
            float v = h0[(size_t)(g * 16 + m) * 256 + col];
            hprev[ji][r] = v;
            Ah[m][col] = (bf16)v;
        }
    }
    STAGE(0, 0);
    __syncthreads();   // one-time full drain (tile 0 + Ah staged)

    for (int t = 0; t < TT; ++t) {
        const int slot = t & 1;
        // ---- phase 1: issue next tile, MFMA over Ah ----
        STAGE((t + 1 < TT) ? t + 1 : TT - 1, slot ^ 1);
        f32x4 cr[2], cz[2], cn[2];
#pragma unroll
        for (int i = 0; i < 2; ++i) {
            cr[i] = (f32x4){0.f,0.f,0.f,0.f};
            cz[i] = (f32x4){0.f,0.f,0.f,0.f};
            cn[i] = (f32x4){0.f,0.f,0.f,0.f};
        }
#pragma unroll
        for (int kk = 0; kk < 8; ++kk) {
            bf16x8 a = *(const bf16x8*)&Ah[cl][kk * 32 + lh * 8];
#pragma unroll
            for (int ji = 0; ji < 2; ++ji) {
                cr[ji] = mfma16(a, Br[ji][kk], cr[ji]);
                cz[ji] = mfma16(a, Bz[ji][kk], cz[ji]);
                cn[ji] = mfma16(a, Bn[ji][kk], cn[ji]);
            }
        }
        asm volatile("s_waitcnt lgkmcnt(0)" ::: "memory");
        __builtin_amdgcn_sched_barrier(0);
        __builtin_amdgcn_s_barrier();          // A: all Ah reads done
        __builtin_amdgcn_sched_barrier(0);

        // ---- tile t ready? (newer ops: 1 Y-store + 4 next-tile loads) ----
        if (t == 0) asm volatile("s_waitcnt vmcnt(4)" ::: "memory");
        else        asm volatile("s_waitcnt vmcnt(5)" ::: "memory");
        __builtin_amdgcn_sched_barrier(0);

        // ---- gates: gx from LDS, h update, Ah write ----
#pragma unroll
        for (int ji = 0; ji < 2; ++ji) {
            const int col = (2 * w + ji) * 16 + cl;
#pragma unroll
            for (int r = 0; r < 4; ++r) {
                const int m = 4 * lh + r;
                unsigned int rzu = *(const unsigned int*)&gxl[slot][0][m][col * 4];
                float gnv        = *(const float*)       &gxl[slot][1][m][col * 4];
                fp16x2 rz = __builtin_bit_cast(fp16x2, rzu);
                float rr_ = sigf((float)rz[0] + cr[ji][r]);
                float zz  = sigf((float)rz[1] + cz[ji][r]);
                float nn  = tanhfast(gnv + rr_ * (cn[ji][r] + bN[ji]));
                float hnew = (1.f - zz) * nn + zz * hprev[ji][r];
                hprev[ji][r] = hnew;
                Ah[m][col] = (bf16)hnew;
                if (t == TT - 1) hnfL[(size_t)(g * 16 + m) * 768 + col] = hnew;
            }
        }
        asm volatile("s_waitcnt lgkmcnt(0)" ::: "memory");
        __builtin_amdgcn_sched_barrier(0);
        __builtin_amdgcn_s_barrier();          // B: Ah writes visible
        __builtin_amdgcn_sched_barrier(0);

        // ---- vectorized Y epilogue (store stays in flight) ----
        {
            const int yrow = tid >> 5;          // 0..15
            const int yc   = (tid & 31) * 8;    // 0..248
            bf16x8 yv = *(const bf16x8*)&Ah[yrow][yc];
            *(bf16x8*)(Y + ((size_t)t * BB + g * 16 + yrow) * 256 + yc) = yv;
        }
    }
}

// ---------------------------------------------------------------------------
__global__ __launch_bounds__(256) void fc_out(const float* __restrict__ hn,
                                              const float* __restrict__ fcw,
                                              const float* __restrict__ fcb,
                                              float* __restrict__ out)
{
    __shared__ float hs[768];
    const int b = blockIdx.x;
    for (int i = threadIdx.x; i < 768; i += 256) hs[i] = hn[(size_t)b * 768 + i];
    __syncthreads();
    for (int i = threadIdx.x; i < H_IN; i += 256) {
        const float4* wr = (const float4*)(fcw + (size_t)i * 768);
        float a0 = 0.f, a1 = 0.f, a2 = 0.f, a3 = 0.f;
#pragma unroll 4
        for (int c = 0; c < 192; ++c) {
            float4 wv = wr[c];
            const float* h4 = &hs[c * 4];
            a0 += wv.x * h4[0]; a1 += wv.y * h4[1];
            a2 += wv.z * h4[2]; a3 += wv.w * h4[3];
        }
        out[(size_t)b * H_IN + i] = fcb[i] + a0 + a1 + a2 + a3;
    }
}

extern "C" void kernel_launch(void* const* d_in, const int* in_sizes, int n_in,
                              void* d_out, int out_size, void* d_ws, size_t ws_size,
                              hipStream_t stream) {
    const float* X    = (const float*)d_in[0];
    const float* hid  = (const float*)d_in[1];
    const float* wih0 = (const float*)d_in[2];
    const float* whh0 = (const float*)d_in[3];
    const float* bih0 = (const float*)d_in[4];
    const float* bhh0 = (const float*)d_in[5];
    const float* wih1 = (const float*)d_in[6];
    const float* whh1 = (const float*)d_in[7];
    const float* bih1 = (const float*)d_in[8];
    const float* bhh1 = (const float*)d_in[9];
    const float* wih2 = (const float*)d_in[10];
    const float* whh2 = (const float*)d_in[11];
    const float* bih2 = (const float*)d_in[12];
    const float* bhh2 = (const float*)d_in[13];
    const float* fcw  = (const float*)d_in[14];
    const float* fcb  = (const float*)d_in[15];
    float* out = (float*)d_out;

    // Layout (total 43,525,120 B — within the known-safe 52.7 MB):
    char* ws = (char*)d_ws;
    bf16*  Wh    = (bf16*)ws;                      //          0 .. 1,179,648
    float* hnf   = (float*)(ws + 1188864);         //  1,188,864 .. 1,582,080
    bf16*  Y     = (bf16*)(ws + 1582080);          //  1,582,080 .. 9,970,688
    float* gxn   = (float*)(ws + 9970688);         //  9,970,688 .. 26,747,904
    char*  gxrzb = ws + 26747904;                  // 26,747,904 .. 43,525,120
    const unsigned int* grzp = (const unsigned int*)gxrzb;

    prep_pack2<<<dim3(1152), dim3(512), 0, stream>>>(whh0, whh1, whh2, Wh);
    // layer 0
    gemm_gx0<<<dim3(128, 3), dim3(512), 0, stream>>>(X, wih0, bih0, bhh0, gxrzb, gxn);
    gru_rec<<<dim3(8), dim3(512), 0, stream>>>(grzp, gxn, Wh, bhh0,
                                               hid, Y, hnf);
    // layer 1
    gemm_gxy<<<dim3(128, 3), dim3(512), 0, stream>>>(Y, wih1, bih1, bhh1, gxrzb, gxn);
    gru_rec<<<dim3(8), dim3(512), 0, stream>>>(grzp, gxn, Wh + 196608, bhh1,
                                               hid + 32768, Y, hnf + 256);
    // layer 2
    gemm_gxy<<<dim3(128, 3), dim3(512), 0, stream>>>(Y, wih2, bih2, bhh2, gxrzb, gxn);
    gru_rec<<<dim3(8), dim3(512), 0, stream>>>(grzp, gxn, Wh + 393216, bhh2,
                                               hid + 65536, Y, hnf + 512);
    // head
    fc_out<<<dim3(128), dim3(256), 0, stream>>>(hnf, fcw, fcb, out);
    hipMemcpyAsync(out + 171776, hid, 98304 * sizeof(float),
                   hipMemcpyDeviceToDevice, stream);
}

// Round 15
// 1734.976 us; speedup vs baseline: 1.4731x; 1.0104x over previous
//
#include <hip/hip_runtime.h>
#include <hip/hip_bf16.h>

typedef __bf16 bf16;
typedef _Float16 fp16;
typedef __attribute__((ext_vector_type(8))) __bf16 bf16x8;
typedef __attribute__((ext_vector_type(2))) _Float16 fp16x2;
typedef __attribute__((ext_vector_type(4))) float f32x4;
typedef long long i64;

#define H_IN 1342
#define TT   128
#define BB   128

static __device__ __forceinline__ f32x4 mfma16(bf16x8 a, bf16x8 b, f32x4 c) {
    return __builtin_amdgcn_mfma_f32_16x16x32_bf16(a, b, c, 0, 0, 0);
}
static __device__ __forceinline__ f32x4 mfma8(i64 a, i64 b, f32x4 c) {
    return __builtin_amdgcn_mfma_f32_16x16x32_fp8_fp8(a, b, c, 0, 0, 0);
}
static __device__ __forceinline__ float sigf(float x) {
    return 1.f / (1.f + __expf(-x));
}
static __device__ __forceinline__ float tanhfast(float x) {
    return 2.f / (1.f + __expf(-2.f * x)) - 1.f;
}

// float -> OCP e4m3fn with RNE. Subnormal/low region (|x| < 2^-6) is handled
// on the continuous 2^-9 grid (byte values 0..8 line up across the
// subnormal->normal boundary); normals via frexp + 4-bit mantissa rounding.
static __device__ __forceinline__ unsigned char f2e4m3(float x) {
    unsigned char sgn = (unsigned char)((__builtin_bit_cast(unsigned int, x) >> 24) & 0x80);
    float ax = fabsf(x);
    if (ax < 0.015625f) {                       // < 2^-6
        float q = nearbyintf(ax * 512.f);       // RNE, q in [0, 8]
        return sgn | (unsigned char)(int)q;
    }
    if (ax >= 448.f) return sgn | 0x7E;         // clamp to max finite
    int e; float m = frexpf(ax, &e);            // ax = m * 2^e, m in [0.5, 1)
    float q = nearbyintf(m * 16.f);             // [8, 16]
    int E = e - 1;
    if (q == 16.f) { q = 8.f; E += 1; }
    if (E > 8) return sgn | 0x7E;
    return sgn | (unsigned char)((E + 7) << 3) | (unsigned char)((int)q & 7);
}

// ---------------------------------------------------------------------------
// Pack the three w_hh matrices (768x256) into fp8 MFMA B-fragment order.
// Same frag indexing as the verified bf16 pack; 1 B/elem (frag = 512 B).
// ---------------------------------------------------------------------------
__global__ void prep_pack2(const float* __restrict__ whh0,
                           const float* __restrict__ whh1,
                           const float* __restrict__ whh2,
                           unsigned char* __restrict__ Wh8)
{
    int idx = blockIdx.x * blockDim.x + threadIdx.x;
    if (idx < 589824) {
        int l = idx / 196608;
        int r = idx - l * 196608;
        const float* w = (l == 0) ? whh0 : (l == 1) ? whh1 : whh2;
        int f = r >> 9, q = r & 511;
        int lane = q >> 3, j = q & 7;
        int nt = f >> 3, kt = f & 7;
        int n = nt * 16 + (lane & 15);
        int k = kt * 32 + (lane >> 4) * 8 + j;
        Wh8[idx] = f2e4m3(w[n * 256 + k]);
    }
}

// ---------------------------------------------------------------------------
// Layer-0 input GEMM. Epilogue: r,z -> interleaved fp16x2 dword plane
// (lo=r, hi=z, b_hh folded), n -> fp32 plane. (round-6..14 verified)
// ---------------------------------------------------------------------------
__global__ __launch_bounds__(512) void gemm_gx0(const float* __restrict__ X,
                                                const float* __restrict__ W,
                                                const float* __restrict__ bih,
                                                const float* __restrict__ bhh,
                                                char*  __restrict__ gxrz2b,
                                                float* __restrict__ gxn)
{
    __shared__ bf16 As[128][40];
    __shared__ bf16 Bs[256][40];
    const int tid  = threadIdx.x;
    const int lane = tid & 63;
    const int w    = tid >> 6;
    const int cl   = lane & 15;
    const int lh   = lane >> 4;
    const int rm0  = blockIdx.x * 128;
    const int n0   = blockIdx.y * 256;

    f32x4 acc[16];
#pragma unroll
    for (int i = 0; i < 16; ++i) acc[i] = (f32x4){0.f, 0.f, 0.f, 0.f};

    for (int kt = 0; kt < 42; ++kt) {
        const int k0 = kt * 32;
        {
            int row = tid >> 2;
            int c   = (tid & 3) * 8;
            const float* src = X + (size_t)(rm0 + row) * H_IN + (k0 + c);
            bf16x8 pk;
            if (k0 + c + 8 <= H_IN) {
                const float2* s2 = (const float2*)src;
                float2 v0 = s2[0], v1 = s2[1], v2 = s2[2], v3 = s2[3];
                pk[0] = (bf16)v0.x; pk[1] = (bf16)v0.y; pk[2] = (bf16)v1.x; pk[3] = (bf16)v1.y;
                pk[4] = (bf16)v2.x; pk[5] = (bf16)v2.y; pk[6] = (bf16)v3.x; pk[7] = (bf16)v3.y;
            } else {
#pragma unroll
                for (int i = 0; i < 8; ++i)
                    pk[i] = (bf16)((k0 + c + i < H_IN) ? src[i] : 0.f);
            }
            *(bf16x8*)&As[row][c] = pk;
        }
        {
            int row = tid >> 1;
            int c   = (tid & 1) * 16;
            const float* src = W + (size_t)(n0 + row) * H_IN + (k0 + c);
#pragma unroll
            for (int h = 0; h < 2; ++h) {
                const float* s = src + h * 8;
                bf16x8 pk;
                if (k0 + c + h * 8 + 8 <= H_IN) {
                    const float2* s2 = (const float2*)s;
                    float2 v0 = s2[0], v1 = s2[1], v2 = s2[2], v3 = s2[3];
                    pk[0] = (bf16)v0.x; pk[1] = (bf16)v0.y; pk[2] = (bf16)v1.x; pk[3] = (bf16)v1.y;
                    pk[4] = (bf16)v2.x; pk[5] = (bf16)v2.y; pk[6] = (bf16)v3.x; pk[7] = (bf16)v3.y;
                } else {
#pragma unroll
                    for (int i = 0; i < 8; ++i)
                        pk[i] = (bf16)((k0 + c + h * 8 + i < H_IN) ? s[i] : 0.f);
                }
                *(bf16x8*)&Bs[row][c + h * 8] = pk;
            }
        }
        __syncthreads();
        bf16x8 a = *(const bf16x8*)&As[w * 16 + cl][lh * 8];
#pragma unroll
        for (int nt = 0; nt < 16; ++nt) {
            bf16x8 b = *(const bf16x8*)&Bs[nt * 16 + cl][lh * 8];
            acc[nt] = mfma16(a, b, acc[nt]);
        }
        __syncthreads();
    }
#pragma unroll
    for (int nt = 0; nt < 16; ++nt) {
#pragma unroll
        for (int r = 0; r < 4; ++r) {
            int rm  = rm0 + w * 16 + 4 * lh + r;
            int col = n0 + nt * 16 + cl;
            int b = rm >> 7, t = rm & 127;          // X rows are b*128+t
            size_t ro = (size_t)t * BB + b;
            if (col < 512) {
                float v = acc[nt][r] + bih[col] + bhh[col];
                *(fp16*)(gxrz2b + ro * 1024 + (col & 255) * 4 + (col >> 8) * 2) = (fp16)v;
            } else {
                gxn[ro * 256 + (col - 512)] = acc[nt][r] + bih[col];
            }
        }
    }
}

// ---------------------------------------------------------------------------
// Layers 1/2 input GEMM: same epilogue; A = Y bf16 [t*128+b][256].
// ---------------------------------------------------------------------------
__global__ __launch_bounds__(512) void gemm_gxy(const bf16* __restrict__ Y,
                                                const float* __restrict__ W,
                                                const float* __restrict__ bih,
                                                const float* __restrict__ bhh,
                                                char*  __restrict__ gxrz2b,
                                                float* __restrict__ gxn)
{
    __shared__ bf16 As[128][40];
    __shared__ bf16 Bs[256][40];
    const int tid  = threadIdx.x;
    const int lane = tid & 63;
    const int w    = tid >> 6;
    const int cl   = lane & 15;
    const int lh   = lane >> 4;
    const int rm0  = blockIdx.x * 128;
    const int n0   = blockIdx.y * 256;

    f32x4 acc[16];
#pragma unroll
    for (int i = 0; i < 16; ++i) acc[i] = (f32x4){0.f, 0.f, 0.f, 0.f};

    for (int kt = 0; kt < 8; ++kt) {
        const int k0 = kt * 32;
        {
            int row = tid >> 2;
            int c   = (tid & 3) * 8;
            *(bf16x8*)&As[row][c] =
                *(const bf16x8*)(Y + (size_t)(rm0 + row) * 256 + k0 + c);
        }
        {
            int row = tid >> 1;
            int c   = (tid & 1) * 16;
            const float* src = W + (size_t)(n0 + row) * 256 + (k0 + c);
#pragma unroll
            for (int h = 0; h < 2; ++h) {
                const float2* s2 = (const float2*)(src + h * 8);
                float2 v0 = s2[0], v1 = s2[1], v2 = s2[2], v3 = s2[3];
                bf16x8 pk;
                pk[0] = (bf16)v0.x; pk[1] = (bf16)v0.y; pk[2] = (bf16)v1.x; pk[3] = (bf16)v1.y;
                pk[4] = (bf16)v2.x; pk[5] = (bf16)v2.y; pk[6] = (bf16)v3.x; pk[7] = (bf16)v3.y;
                *(bf16x8*)&Bs[row][c + h * 8] = pk;
            }
        }
        __syncthreads();
        bf16x8 a = *(const bf16x8*)&As[w * 16 + cl][lh * 8];
#pragma unroll
        for (int nt = 0; nt < 16; ++nt) {
            bf16x8 b = *(const bf16x8*)&Bs[nt * 16 + cl][lh * 8];
            acc[nt] = mfma16(a, b, acc[nt]);
        }
        __syncthreads();
    }
#pragma unroll
    for (int nt = 0; nt < 16; ++nt) {
#pragma unroll
        for (int r = 0; r < 4; ++r) {
            size_t rm = (size_t)(rm0 + w * 16 + 4 * lh + r);   // = t*128 + b
            int col = n0 + nt * 16 + cl;
            if (col < 512) {
                float v = acc[nt][r] + bih[col] + bhh[col];
                *(fp16*)(gxrz2b + rm * 1024 + (col & 255) * 4 + (col >> 8) * 2) = (fp16)v;
            } else {
                gxn[rm * 256 + (col - 512)] = acc[nt][r] + bih[col];
            }
        }
    }
}

// ---------------------------------------------------------------------------
// Recurrent layer v10 = round-9 structure with fp8 weights + fp8 A-operand.
// 48 B-frags are now 2 VGPRs each (96 total) — half the streamed bytes if
// the allocator still re-streams, and small enough to fit its 128-reg
// budget if it chooses residency. h kept fp32 in regs, bf16 in Ah (for Y),
// fp8 in Ah8 (MFMA A).
// ---------------------------------------------------------------------------
__global__ __launch_bounds__(512)
void gru_rec(
    const unsigned int* __restrict__ grzp,  // [T*B][256] dwords: (fp16 r, fp16 z)
    const float* __restrict__ gxn,          // [T*B][256] fp32 (n, incl b_ih)
    const unsigned char* __restrict__ Wh8,  // this layer's fp8 hh pack (196608 B)
    const float* __restrict__ bhh,          // raw b_hh (768); only n-part used
    const float* __restrict__ h0,           // hidden + l*128*256
    bf16*  __restrict__ Y,                  // [T*B][256] bf16 out
    float* __restrict__ hnfL)               // hnf + l*256 (stride 768)
{
    __shared__ bf16 Ah[16][264];                       // bf16 h (Y epilogue)
    __shared__ unsigned char Ah8[16][264];             // fp8 h (MFMA A)
    __shared__ __align__(16) char gxl[2][2][16][1040]; // gx ring

    const int tid  = threadIdx.x;
    const int lane = tid & 63;
    const int w    = tid >> 6;              // 0..7
    const int cl   = lane & 15;
    const int lh   = lane >> 4;
    const int g    = blockIdx.x;

    // ---- 48 fp8 B-fragments -> registers (8 B each) ----
    i64 Br[2][8], Bz[2][8], Bn[2][8];
#pragma unroll
    for (int ji = 0; ji < 2; ++ji) {
        const int jt = 2 * w + ji;
#pragma unroll
        for (int kk = 0; kk < 8; ++kk) {
            Br[ji][kk] = *(const i64*)(Wh8 + (size_t)(( jt       * 8 + kk) * 512) + lane * 8);
            Bz[ji][kk] = *(const i64*)(Wh8 + (size_t)(((16 + jt) * 8 + kk) * 512) + lane * 8);
            Bn[ji][kk] = *(const i64*)(Wh8 + (size_t)(((32 + jt) * 8 + kk) * 512) + lane * 8);
        }
    }
    float bN[2];
#pragma unroll
    for (int ji = 0; ji < 2; ++ji)
        bN[ji] = bhh[512 + (2 * w + ji) * 16 + cl];

    // gx tile stage: wave w stages rows {2w, 2w+1} of both planes (DMA, 16B/lane)
    auto STAGE = [&](int tt, int slot) {
#pragma unroll
        for (int i = 0; i < 2; ++i) {
            const int row = 2 * w + i;
            const size_t gr = (size_t)tt * BB + g * 16 + row;
            const unsigned int* s0 = grzp + gr * 256 + lane * 4;
            const float*        s1 = gxn  + gr * 256 + lane * 4;
            __builtin_amdgcn_global_load_lds(
                (const __attribute__((address_space(1))) void*)s0,
                (__attribute__((address_space(3))) void*)&gxl[slot][0][row][0], 16, 0, 0);
            __builtin_amdgcn_global_load_lds(
                (const __attribute__((address_space(1))) void*)s1,
                (__attribute__((address_space(3))) void*)&gxl[slot][1][row][0], 16, 0, 0);
        }
    };

    // ---- prologue: h0 -> regs + Ah/Ah8; issue tile 0 ----
    float hprev[2][4];
#pragma unroll
    for (int ji = 0; ji < 2; ++ji) {
        const int col = (2 * w + ji) * 16 + cl;
#pragma unroll
        for (int r = 0; r < 4; ++r) {
            const int m = 4 * lh + r;
            float v = h0[(size_t)(g * 16 + m) * 256 + col];
            hprev[ji][r] = v;
            Ah[m][col]  = (bf16)v;
            Ah8[m][col] = f2e4m3(v);
        }
    }
    STAGE(0, 0);
    __syncthreads();   // one-time full drain (tile 0 + Ah staged)

    for (int t = 0; t < TT; ++t) {
        const int slot = t & 1;
        // ---- phase 1: issue next tile, fp8 MFMA over Ah8 ----
        STAGE((t + 1 < TT) ? t + 1 : TT - 1, slot ^ 1);
        f32x4 cr[2], cz[2], cn[2];
#pragma unroll
        for (int i = 0; i < 2; ++i) {
            cr[i] = (f32x4){0.f,0.f,0.f,0.f};
            cz[i] = (f32x4){0.f,0.f,0.f,0.f};
            cn[i] = (f32x4){0.f,0.f,0.f,0.f};
        }
#pragma unroll
        for (int kk = 0; kk < 8; ++kk) {
            i64 a = *(const i64*)&Ah8[cl][kk * 32 + lh * 8];
#pragma unroll
            for (int ji = 0; ji < 2; ++ji) {
                cr[ji] = mfma8(a, Br[ji][kk], cr[ji]);
                cz[ji] = mfma8(a, Bz[ji][kk], cz[ji]);
                cn[ji] = mfma8(a, Bn[ji][kk], cn[ji]);
            }
        }
        asm volatile("s_waitcnt lgkmcnt(0)" ::: "memory");
        __builtin_amdgcn_sched_barrier(0);
        __builtin_amdgcn_s_barrier();          // A: all Ah8 reads done
        __builtin_amdgcn_sched_barrier(0);

        // ---- tile t ready? (newer ops: 1 Y-store + 4 next-tile loads) ----
        if (t == 0) asm volatile("s_waitcnt vmcnt(4)" ::: "memory");
        else        asm volatile("s_waitcnt vmcnt(5)" ::: "memory");
        __builtin_amdgcn_sched_barrier(0);

        // ---- gates: gx from LDS, h update, Ah/Ah8 write ----
#pragma unroll
        for (int ji = 0; ji < 2; ++ji) {
            const int col = (2 * w + ji) * 16 + cl;
#pragma unroll
            for (int r = 0; r < 4; ++r) {
                const int m = 4 * lh + r;
                unsigned int rzu = *(const unsigned int*)&gxl[slot][0][m][col * 4];
                float gnv        = *(const float*)       &gxl[slot][1][m][col * 4];
                fp16x2 rz = __builtin_bit_cast(fp16x2, rzu);
                float rr_ = sigf((float)rz[0] + cr[ji][r]);
                float zz  = sigf((float)rz[1] + cz[ji][r]);
                float nn  = tanhfast(gnv + rr_ * (cn[ji][r] + bN[ji]));
                float hnew = (1.f - zz) * nn + zz * hprev[ji][r];
                hprev[ji][r] = hnew;
                Ah[m][col]  = (bf16)hnew;
                Ah8[m][col] = f2e4m3(hnew);
                if (t == TT - 1) hnfL[(size_t)(g * 16 + m) * 768 + col] = hnew;
            }
        }
        asm volatile("s_waitcnt lgkmcnt(0)" ::: "memory");
        __builtin_amdgcn_sched_barrier(0);
        __builtin_amdgcn_s_barrier();          // B: Ah/Ah8 writes visible
        __builtin_amdgcn_sched_barrier(0);

        // ---- vectorized Y epilogue (store stays in flight) ----
        {
            const int yrow = tid >> 5;          // 0..15
            const int yc   = (tid & 31) * 8;    // 0..248
            bf16x8 yv = *(const bf16x8*)&Ah[yrow][yc];
            *(bf16x8*)(Y + ((size_t)t * BB + g * 16 + yrow) * 256 + yc) = yv;
        }
    }
}

// ---------------------------------------------------------------------------
__global__ __launch_bounds__(256) void fc_out(const float* __restrict__ hn,
                                              const float* __restrict__ fcw,
                                              const float* __restrict__ fcb,
                                              float* __restrict__ out)
{
    __shared__ float hs[768];
    const int b = blockIdx.x;
    for (int i = threadIdx.x; i < 768; i += 256) hs[i] = hn[(size_t)b * 768 + i];
    __syncthreads();
    for (int i = threadIdx.x; i < H_IN; i += 256) {
        const float4* wr = (const float4*)(fcw + (size_t)i * 768);
        float a0 = 0.f, a1 = 0.f, a2 = 0.f, a3 = 0.f;
#pragma unroll 4
        for (int c = 0; c < 192; ++c) {
            float4 wv = wr[c];
            const float* h4 = &hs[c * 4];
            a0 += wv.x * h4[0]; a1 += wv.y * h4[1];
            a2 += wv.z * h4[2]; a3 += wv.w * h4[3];
        }
        out[(size_t)b * H_IN + i] = fcb[i] + a0 + a1 + a2 + a3;
    }
}

extern "C" void kernel_launch(void* const* d_in, const int* in_sizes, int n_in,
                              void* d_out, int out_size, void* d_ws, size_t ws_size,
                              hipStream_t stream) {
    const float* X    = (const float*)d_in[0];
    const float* hid  = (const float*)d_in[1];
    const float* wih0 = (const float*)d_in[2];
    const float* whh0 = (const float*)d_in[3];
    const float* bih0 = (const float*)d_in[4];
    const float* bhh0 = (const float*)d_in[5];
    const float* wih1 = (const float*)d_in[6];
    const float* whh1 = (const float*)d_in[7];
    const float* bih1 = (const float*)d_in[8];
    const float* bhh1 = (const float*)d_in[9];
    const float* wih2 = (const float*)d_in[10];
    const float* whh2 = (const float*)d_in[11];
    const float* bih2 = (const float*)d_in[12];
    const float* bhh2 = (const float*)d_in[13];
    const float* fcw  = (const float*)d_in[14];
    const float* fcb  = (const float*)d_in[15];
    float* out = (float*)d_out;

    // Layout (total 43,525,120 B — within the known-safe 52.7 MB):
    char* ws = (char*)d_ws;
    unsigned char* Wh8 = (unsigned char*)ws;       //          0 ..   589,824
    float* hnf   = (float*)(ws + 1188864);         //  1,188,864 .. 1,582,080
    bf16*  Y     = (bf16*)(ws + 1582080);          //  1,582,080 .. 9,970,688
    float* gxn   = (float*)(ws + 9970688);         //  9,970,688 .. 26,747,904
    char*  gxrzb = ws + 26747904;                  // 26,747,904 .. 43,525,120
    const unsigned int* grzp = (const unsigned int*)gxrzb;

    prep_pack2<<<dim3(1152), dim3(512), 0, stream>>>(whh0, whh1, whh2, Wh8);
    // layer 0
    gemm_gx0<<<dim3(128, 3), dim3(512), 0, stream>>>(X, wih0, bih0, bhh0, gxrzb, gxn);
    gru_rec<<<dim3(8), dim3(512), 0, stream>>>(grzp, gxn, Wh8, bhh0,
                                               hid, Y, hnf);
    // layer 1
    gemm_gxy<<<dim3(128, 3), dim3(512), 0, stream>>>(Y, wih1, bih1, bhh1, gxrzb, gxn);
    gru_rec<<<dim3(8), dim3(512), 0, stream>>>(grzp, gxn, Wh8 + 196608, bhh1,
                                               hid + 32768, Y, hnf + 256);
    // layer 2
    gemm_gxy<<<dim3(128, 3), dim3(512), 0, stream>>>(Y, wih2, bih2, bhh2, gxrzb, gxn);
    gru_rec<<<dim3(8), dim3(512), 0, stream>>>(grzp, gxn, Wh8 + 393216, bhh2,
                                               hid + 65536, Y, hnf + 512);
    // head
    fc_out<<<dim3(128), dim3(256), 0, stream>>>(hnf, fcw, fcb, out);
    hipMemcpyAsync(out + 171776, hid, 98304 * sizeof(float),
                   hipMemcpyDeviceToDevice, stream);
}

// Round 16
// 1365.796 us; speedup vs baseline: 1.8713x; 1.2703x over previous
//
#include <hip/hip_runtime.h>
#include <hip/hip_bf16.h>

typedef __bf16 bf16;
typedef _Float16 fp16;
typedef __attribute__((ext_vector_type(8))) __bf16 bf16x8;
typedef __attribute__((ext_vector_type(2))) _Float16 fp16x2;
typedef __attribute__((ext_vector_type(4))) float f32x4;
typedef long long i64;

#define H_IN 1342
#define TT   128
#define BB   128

static __device__ __forceinline__ f32x4 mfma16(bf16x8 a, bf16x8 b, f32x4 c) {
    return __builtin_amdgcn_mfma_f32_16x16x32_bf16(a, b, c, 0, 0, 0);
}
static __device__ __forceinline__ f32x4 mfma8(i64 a, i64 b, f32x4 c) {
    return __builtin_amdgcn_mfma_f32_16x16x32_fp8_fp8(a, b, c, 0, 0, 0);
}
static __device__ __forceinline__ float sigf(float x) {
    return 1.f / (1.f + __expf(-x));
}
static __device__ __forceinline__ float tanhfast(float x) {
    return 2.f / (1.f + __expf(-2.f * x)) - 1.f;
}

// float -> OCP e4m3fn with RNE (software path; used in one-time packing).
static __device__ __forceinline__ unsigned char f2e4m3(float x) {
    unsigned char sgn = (unsigned char)((__builtin_bit_cast(unsigned int, x) >> 24) & 0x80);
    float ax = fabsf(x);
    if (ax < 0.015625f) {
        float q = nearbyintf(ax * 512.f);
        return sgn | (unsigned char)(int)q;
    }
    if (ax >= 448.f) return sgn | 0x7E;
    int e; float m = frexpf(ax, &e);
    float q = nearbyintf(m * 16.f);
    int E = e - 1;
    if (q == 16.f) { q = 8.f; E += 1; }
    if (E > 8) return sgn | 0x7E;
    return sgn | (unsigned char)((E + 7) << 3) | (unsigned char)((int)q & 7);
}

// Packed f32x2 -> 2 fp8 bytes (hardware if available).
static __device__ __forceinline__ unsigned int pk_fp8(float a, float b) {
#if __has_builtin(__builtin_amdgcn_cvt_pk_fp8_f32)
    return (unsigned int)__builtin_amdgcn_cvt_pk_fp8_f32(a, b, 0, false);
#else
    return (unsigned int)f2e4m3(a) | ((unsigned int)f2e4m3(b) << 8);
#endif
}

// ---------------------------------------------------------------------------
// Pack the three w_hh matrices (768x256) into fp8 MFMA B-fragment order.
// ---------------------------------------------------------------------------
__global__ void prep_pack2(const float* __restrict__ whh0,
                           const float* __restrict__ whh1,
                           const float* __restrict__ whh2,
                           unsigned char* __restrict__ Wh8)
{
    int idx = blockIdx.x * blockDim.x + threadIdx.x;
    if (idx < 589824) {
        int l = idx / 196608;
        int r = idx - l * 196608;
        const float* w = (l == 0) ? whh0 : (l == 1) ? whh1 : whh2;
        int f = r >> 9, q = r & 511;
        int lane = q >> 3, j = q & 7;
        int nt = f >> 3, kt = f & 7;
        int n = nt * 16 + (lane & 15);
        int k = kt * 32 + (lane >> 4) * 8 + j;
        Wh8[idx] = f2e4m3(w[n * 256 + k]);
    }
}

// ---------------------------------------------------------------------------
// Layer-0 input GEMM. Epilogue: r,z -> interleaved fp16x2 dword plane
// (lo=r, hi=z, b_hh folded), n -> fp32 plane. (round-6..15 verified)
// ---------------------------------------------------------------------------
__global__ __launch_bounds__(512) void gemm_gx0(const float* __restrict__ X,
                                                const float* __restrict__ W,
                                                const float* __restrict__ bih,
                                                const float* __restrict__ bhh,
                                                char*  __restrict__ gxrz2b,
                                                float* __restrict__ gxn)
{
    __shared__ bf16 As[128][40];
    __shared__ bf16 Bs[256][40];
    const int tid  = threadIdx.x;
    const int lane = tid & 63;
    const int w    = tid >> 6;
    const int cl   = lane & 15;
    const int lh   = lane >> 4;
    const int rm0  = blockIdx.x * 128;
    const int n0   = blockIdx.y * 256;

    f32x4 acc[16];
#pragma unroll
    for (int i = 0; i < 16; ++i) acc[i] = (f32x4){0.f, 0.f, 0.f, 0.f};

    for (int kt = 0; kt < 42; ++kt) {
        const int k0 = kt * 32;
        {
            int row = tid >> 2;
            int c   = (tid & 3) * 8;
            const float* src = X + (size_t)(rm0 + row) * H_IN + (k0 + c);
            bf16x8 pk;
            if (k0 + c + 8 <= H_IN) {
                const float2* s2 = (const float2*)src;
                float2 v0 = s2[0], v1 = s2[1], v2 = s2[2], v3 = s2[3];
                pk[0] = (bf16)v0.x; pk[1] = (bf16)v0.y; pk[2] = (bf16)v1.x; pk[3] = (bf16)v1.y;
                pk[4] = (bf16)v2.x; pk[5] = (bf16)v2.y; pk[6] = (bf16)v3.x; pk[7] = (bf16)v3.y;
            } else {
#pragma unroll
                for (int i = 0; i < 8; ++i)
                    pk[i] = (bf16)((k0 + c + i < H_IN) ? src[i] : 0.f);
            }
            *(bf16x8*)&As[row][c] = pk;
        }
        {
            int row = tid >> 1;
            int c   = (tid & 1) * 16;
            const float* src = W + (size_t)(n0 + row) * H_IN + (k0 + c);
#pragma unroll
            for (int h = 0; h < 2; ++h) {
                const float* s = src + h * 8;
                bf16x8 pk;
                if (k0 + c + h * 8 + 8 <= H_IN) {
                    const float2* s2 = (const float2*)s;
                    float2 v0 = s2[0], v1 = s2[1], v2 = s2[2], v3 = s2[3];
                    pk[0] = (bf16)v0.x; pk[1] = (bf16)v0.y; pk[2] = (bf16)v1.x; pk[3] = (bf16)v1.y;
                    pk[4] = (bf16)v2.x; pk[5] = (bf16)v2.y; pk[6] = (bf16)v3.x; pk[7] = (bf16)v3.y;
                } else {
#pragma unroll
                    for (int i = 0; i < 8; ++i)
                        pk[i] = (bf16)((k0 + c + h * 8 + i < H_IN) ? s[i] : 0.f);
                }
                *(bf16x8*)&Bs[row][c + h * 8] = pk;
            }
        }
        __syncthreads();
        bf16x8 a = *(const bf16x8*)&As[w * 16 + cl][lh * 8];
#pragma unroll
        for (int nt = 0; nt < 16; ++nt) {
            bf16x8 b = *(const bf16x8*)&Bs[nt * 16 + cl][lh * 8];
            acc[nt] = mfma16(a, b, acc[nt]);
        }
        __syncthreads();
    }
#pragma unroll
    for (int nt = 0; nt < 16; ++nt) {
#pragma unroll
        for (int r = 0; r < 4; ++r) {
            int rm  = rm0 + w * 16 + 4 * lh + r;
            int col = n0 + nt * 16 + cl;
            int b = rm >> 7, t = rm & 127;          // X rows are b*128+t
            size_t ro = (size_t)t * BB + b;
            if (col < 512) {
                float v = acc[nt][r] + bih[col] + bhh[col];
                *(fp16*)(gxrz2b + ro * 1024 + (col & 255) * 4 + (col >> 8) * 2) = (fp16)v;
            } else {
                gxn[ro * 256 + (col - 512)] = acc[nt][r] + bih[col];
            }
        }
    }
}

// ---------------------------------------------------------------------------
// Layers 1/2 input GEMM: same epilogue; A = Y bf16 [t*128+b][256].
// ---------------------------------------------------------------------------
__global__ __launch_bounds__(512) void gemm_gxy(const bf16* __restrict__ Y,
                                                const float* __restrict__ W,
                                                const float* __restrict__ bih,
                                                const float* __restrict__ bhh,
                                                char*  __restrict__ gxrz2b,
                                                float* __restrict__ gxn)
{
    __shared__ bf16 As[128][40];
    __shared__ bf16 Bs[256][40];
    const int tid  = threadIdx.x;
    const int lane = tid & 63;
    const int w    = tid >> 6;
    const int cl   = lane & 15;
    const int lh   = lane >> 4;
    const int rm0  = blockIdx.x * 128;
    const int n0   = blockIdx.y * 256;

    f32x4 acc[16];
#pragma unroll
    for (int i = 0; i < 16; ++i) acc[i] = (f32x4){0.f, 0.f, 0.f, 0.f};

    for (int kt = 0; kt < 8; ++kt) {
        const int k0 = kt * 32;
        {
            int row = tid >> 2;
            int c   = (tid & 3) * 8;
            *(bf16x8*)&As[row][c] =
                *(const bf16x8*)(Y + (size_t)(rm0 + row) * 256 + k0 + c);
        }
        {
            int row = tid >> 1;
            int c   = (tid & 1) * 16;
            const float* src = W + (size_t)(n0 + row) * 256 + (k0 + c);
#pragma unroll
            for (int h = 0; h < 2; ++h) {
                const float2* s2 = (const float2*)(src + h * 8);
                float2 v0 = s2[0], v1 = s2[1], v2 = s2[2], v3 = s2[3];
                bf16x8 pk;
                pk[0] = (bf16)v0.x; pk[1] = (bf16)v0.y; pk[2] = (bf16)v1.x; pk[3] = (bf16)v1.y;
                pk[4] = (bf16)v2.x; pk[5] = (bf16)v2.y; pk[6] = (bf16)v3.x; pk[7] = (bf16)v3.y;
                *(bf16x8*)&Bs[row][c + h * 8] = pk;
            }
        }
        __syncthreads();
        bf16x8 a = *(const bf16x8*)&As[w * 16 + cl][lh * 8];
#pragma unroll
        for (int nt = 0; nt < 16; ++nt) {
            bf16x8 b = *(const bf16x8*)&Bs[nt * 16 + cl][lh * 8];
            acc[nt] = mfma16(a, b, acc[nt]);
        }
        __syncthreads();
    }
#pragma unroll
    for (int nt = 0; nt < 16; ++nt) {
#pragma unroll
        for (int r = 0; r < 4; ++r) {
            size_t rm = (size_t)(rm0 + w * 16 + 4 * lh + r);   // = t*128 + b
            int col = n0 + nt * 16 + cl;
            if (col < 512) {
                float v = acc[nt][r] + bih[col] + bhh[col];
                *(fp16*)(gxrz2b + rm * 1024 + (col & 255) * 4 + (col >> 8) * 2) = (fp16)v;
            } else {
                gxn[rm * 256 + (col - 512)] = acc[nt][r] + bih[col];
            }
        }
    }
}

// ---------------------------------------------------------------------------
// Recurrent layer v11: fp8 weights/A (round-15 numerics) + ONE barrier per
// step via double-buffered h tiles. gates(t) write Ah8[t&1]/Yst[t&1] while
// MFMA(t) reads Ah8[(t-1)&1] and the Y-epilogue(t-1) reads Yst[(t-1)&1] —
// no same-buffer hazard, so MFMA->gates needs no barrier and waves skew
// within a round: one wave's gates (VALU) overlap another's MFMA (matrix
// pipe). Hardware cvt_pk_fp8 replaces software e4m3 in the hot loop.
// ---------------------------------------------------------------------------
__global__ __launch_bounds__(512)
void gru_rec(
    const unsigned int* __restrict__ grzp,  // [T*B][256] dwords: (fp16 r, fp16 z)
    const float* __restrict__ gxn,          // [T*B][256] fp32 (n, incl b_ih)
    const unsigned char* __restrict__ Wh8,  // this layer's fp8 hh pack (196608 B)
    const float* __restrict__ bhh,          // raw b_hh (768); only n-part used
    const float* __restrict__ h0,           // hidden + l*128*256
    bf16*  __restrict__ Y,                  // [T*B][256] bf16 out
    float* __restrict__ hnfL)               // hnf + l*256 (stride 768)
{
    __shared__ unsigned char Ah8[2][16][264];          // fp8 h (MFMA A), db
    __shared__ bf16 Yst[2][16][264];                   // bf16 h (Y stage), db
    __shared__ __align__(16) char gxl[2][2][16][1040]; // gx ring

    const int tid  = threadIdx.x;
    const int lane = tid & 63;
    const int w    = tid >> 6;              // 0..7
    const int cl   = lane & 15;
    const int lh   = lane >> 4;
    const int g    = blockIdx.x;

    // ---- 48 fp8 B-fragments -> registers (8 B each) ----
    i64 Br[2][8], Bz[2][8], Bn[2][8];
#pragma unroll
    for (int ji = 0; ji < 2; ++ji) {
        const int jt = 2 * w + ji;
#pragma unroll
        for (int kk = 0; kk < 8; ++kk) {
            Br[ji][kk] = *(const i64*)(Wh8 + (size_t)(( jt       * 8 + kk) * 512) + lane * 8);
            Bz[ji][kk] = *(const i64*)(Wh8 + (size_t)(((16 + jt) * 8 + kk) * 512) + lane * 8);
            Bn[ji][kk] = *(const i64*)(Wh8 + (size_t)(((32 + jt) * 8 + kk) * 512) + lane * 8);
        }
    }
    float bN[2];
#pragma unroll
    for (int ji = 0; ji < 2; ++ji)
        bN[ji] = bhh[512 + (2 * w + ji) * 16 + cl];

    // gx tile stage: wave w stages rows {2w, 2w+1} of both planes (DMA, 16B/lane)
    auto STAGE = [&](int tt, int slot) {
#pragma unroll
        for (int i = 0; i < 2; ++i) {
            const int row = 2 * w + i;
            const size_t gr = (size_t)tt * BB + g * 16 + row;
            const unsigned int* s0 = grzp + gr * 256 + lane * 4;
            const float*        s1 = gxn  + gr * 256 + lane * 4;
            __builtin_amdgcn_global_load_lds(
                (const __attribute__((address_space(1))) void*)s0,
                (__attribute__((address_space(3))) void*)&gxl[slot][0][row][0], 16, 0, 0);
            __builtin_amdgcn_global_load_lds(
                (const __attribute__((address_space(1))) void*)s1,
                (__attribute__((address_space(3))) void*)&gxl[slot][1][row][0], 16, 0, 0);
        }
    };

    // ---- prologue: h0 -> regs + Ah8[1] (read by MFMA at t=0); issue tile 0 ----
    float hprev[2][4];
#pragma unroll
    for (int ji = 0; ji < 2; ++ji) {
        const int col = (2 * w + ji) * 16 + cl;
#pragma unroll
        for (int r = 0; r < 4; ++r) {
            const int m = 4 * lh + r;
            float v = h0[(size_t)(g * 16 + m) * 256 + col];
            hprev[ji][r] = v;
            Ah8[1][m][col] = f2e4m3(v);
        }
    }
    STAGE(0, 0);
    __syncthreads();   // one-time full drain (tile 0 + Ah8[1] staged)

    const int c0 = (2 * w) * 16 + cl;
    const int c1 = (2 * w + 1) * 16 + cl;

    for (int t = 0; t < TT; ++t) {
        const int slot = t & 1;
        const int rb   = (t + 1) & 1;       // == (t-1)&1 : MFMA read buffer

        // ---- Y epilogue for step t-1 (vectorized; store stays in flight) ----
        if (t > 0) {
            const int yrow = tid >> 5;          // 0..15
            const int yc   = (tid & 31) * 8;    // 0..248
            bf16x8 yv = *(const bf16x8*)&Yst[(t - 1) & 1][yrow][yc];
            *(bf16x8*)(Y + ((size_t)(t - 1) * BB + g * 16 + yrow) * 256 + yc) = yv;
        }
        // ---- issue next gx tile ----
        STAGE((t + 1 < TT) ? t + 1 : TT - 1, slot ^ 1);

        // ---- MFMA over Ah8[rb] (fp8) ----
        f32x4 cr[2], cz[2], cn[2];
#pragma unroll
        for (int i = 0; i < 2; ++i) {
            cr[i] = (f32x4){0.f,0.f,0.f,0.f};
            cz[i] = (f32x4){0.f,0.f,0.f,0.f};
            cn[i] = (f32x4){0.f,0.f,0.f,0.f};
        }
#pragma unroll
        for (int kk = 0; kk < 8; ++kk) {
            i64 a = *(const i64*)&Ah8[rb][cl][kk * 32 + lh * 8];
#pragma unroll
            for (int ji = 0; ji < 2; ++ji) {
                cr[ji] = mfma8(a, Br[ji][kk], cr[ji]);
                cz[ji] = mfma8(a, Bz[ji][kk], cz[ji]);
                cn[ji] = mfma8(a, Bn[ji][kk], cn[ji]);
            }
        }

        // ---- tile t ready? (newer ops: (t>0: 1 Y-store) + 4 next-tile loads) ----
        if (t == 0) asm volatile("s_waitcnt vmcnt(4)" ::: "memory");
        else        asm volatile("s_waitcnt vmcnt(5)" ::: "memory");
        __builtin_amdgcn_sched_barrier(0);

        // ---- gates (no barrier needed: inputs are own registers + tile t) ----
        float hn2[2][4];
#pragma unroll
        for (int ji = 0; ji < 2; ++ji) {
            const int col = (ji == 0) ? c0 : c1;
#pragma unroll
            for (int r = 0; r < 4; ++r) {
                const int m = 4 * lh + r;
                unsigned int rzu = *(const unsigned int*)&gxl[slot][0][m][col * 4];
                float gnv        = *(const float*)       &gxl[slot][1][m][col * 4];
                fp16x2 rz = __builtin_bit_cast(fp16x2, rzu);
                float rr_ = sigf((float)rz[0] + cr[ji][r]);
                float zz  = sigf((float)rz[1] + cz[ji][r]);
                float nn  = tanhfast(gnv + rr_ * (cn[ji][r] + bN[ji]));
                float hnew = (1.f - zz) * nn + zz * hprev[ji][r];
                hprev[ji][r] = hnew;
                hn2[ji][r] = hnew;
                Yst[slot][m][col] = (bf16)hnew;
                if (t == TT - 1) hnfL[(size_t)(g * 16 + m) * 768 + col] = hnew;
            }
        }
        // fp8 h writes (hardware packed conversion, byte extract per column)
#pragma unroll
        for (int r = 0; r < 4; ++r) {
            const int m = 4 * lh + r;
            unsigned int pk = pk_fp8(hn2[0][r], hn2[1][r]);
            Ah8[slot][m][c0] = (unsigned char)(pk & 0xff);
            Ah8[slot][m][c1] = (unsigned char)((pk >> 8) & 0xff);
        }

        asm volatile("s_waitcnt lgkmcnt(0)" ::: "memory");
        __builtin_amdgcn_sched_barrier(0);
        __builtin_amdgcn_s_barrier();          // the ONLY barrier per step
        __builtin_amdgcn_sched_barrier(0);
    }

    // ---- final Y epilogue (t = TT-1) ----
    {
        const int yrow = tid >> 5;
        const int yc   = (tid & 31) * 8;
        bf16x8 yv = *(const bf16x8*)&Yst[(TT - 1) & 1][yrow][yc];
        *(bf16x8*)(Y + ((size_t)(TT - 1) * BB + g * 16 + yrow) * 256 + yc) = yv;
    }
}

// ---------------------------------------------------------------------------
__global__ __launch_bounds__(256) void fc_out(const float* __restrict__ hn,
                                              const float* __restrict__ fcw,
                                              const float* __restrict__ fcb,
                                              float* __restrict__ out)
{
    __shared__ float hs[768];
    const int b = blockIdx.x;
    for (int i = threadIdx.x; i < 768; i += 256) hs[i] = hn[(size_t)b * 768 + i];
    __syncthreads();
    for (int i = threadIdx.x; i < H_IN; i += 256) {
        const float4* wr = (const float4*)(fcw + (size_t)i * 768);
        float a0 = 0.f, a1 = 0.f, a2 = 0.f, a3 = 0.f;
#pragma unroll 4
        for (int c = 0; c < 192; ++c) {
            float4 wv = wr[c];
            const float* h4 = &hs[c * 4];
            a0 += wv.x * h4[0]; a1 += wv.y * h4[1];
            a2 += wv.z * h4[2]; a3 += wv.w * h4[3];
        }
        out[(size_t)b * H_IN + i] = fcb[i] + a0 + a1 + a2 + a3;
    }
}

extern "C" void kernel_launch(void* const* d_in, const int* in_sizes, int n_in,
                              void* d_out, int out_size, void* d_ws, size_t ws_size,
                              hipStream_t stream) {
    const float* X    = (const float*)d_in[0];
    const float* hid  = (const float*)d_in[1];
    const float* wih0 = (const float*)d_in[2];
    const float* whh0 = (const float*)d_in[3];
    const float* bih0 = (const float*)d_in[4];
    const float* bhh0 = (const float*)d_in[5];
    const float* wih1 = (const float*)d_in[6];
    const float* whh1 = (const float*)d_in[7];
    const float* bih1 = (const float*)d_in[8];
    const float* bhh1 = (const float*)d_in[9];
    const float* wih2 = (const float*)d_in[10];
    const float* whh2 = (const float*)d_in[11];
    const float* bih2 = (const float*)d_in[12];
    const float* bhh2 = (const float*)d_in[13];
    const float* fcw  = (const float*)d_in[14];
    const float* fcb  = (const float*)d_in[15];
    float* out = (float*)d_out;

    // Layout (total 43,525,120 B — within the known-safe 52.7 MB):
    char* ws = (char*)d_ws;
    unsigned char* Wh8 = (unsigned char*)ws;       //          0 ..   589,824
    float* hnf   = (float*)(ws + 1188864);         //  1,188,864 .. 1,582,080
    bf16*  Y     = (bf16*)(ws + 1582080);          //  1,582,080 .. 9,970,688
    float* gxn   = (float*)(ws + 9970688);         //  9,970,688 .. 26,747,904
    char*  gxrzb = ws + 26747904;                  // 26,747,904 .. 43,525,120
    const unsigned int* grzp = (const unsigned int*)gxrzb;

    prep_pack2<<<dim3(1152), dim3(512), 0, stream>>>(whh0, whh1, whh2, Wh8);
    // layer 0
    gemm_gx0<<<dim3(128, 3), dim3(512), 0, stream>>>(X, wih0, bih0, bhh0, gxrzb, gxn);
    gru_rec<<<dim3(8), dim3(512), 0, stream>>>(grzp, gxn, Wh8, bhh0,
                                               hid, Y, hnf);
    // layer 1
    gemm_gxy<<<dim3(128, 3), dim3(512), 0, stream>>>(Y, wih1, bih1, bhh1, gxrzb, gxn);
    gru_rec<<<dim3(8), dim3(512), 0, stream>>>(grzp, gxn, Wh8 + 196608, bhh1,
                                               hid + 32768, Y, hnf + 256);
    // layer 2
    gemm_gxy<<<dim3(128, 3), dim3(512), 0, stream>>>(Y, wih2, bih2, bhh2, gxrzb, gxn);
    gru_rec<<<dim3(8), dim3(512), 0, stream>>>(grzp, gxn, Wh8 + 393216, bhh2,
                                               hid + 65536, Y, hnf + 512);
    // head
    fc_out<<<dim3(128), dim3(256), 0, stream>>>(hnf, fcw, fcb, out);
    hipMemcpyAsync(out + 171776, hid, 98304 * sizeof(float),
                   hipMemcpyDeviceToDevice, stream);
}

// Round 17
// 1270.771 us; speedup vs baseline: 2.0112x; 1.0748x over previous
//
#include <hip/hip_runtime.h>
#include <hip/hip_bf16.h>

typedef __bf16 bf16;
typedef _Float16 fp16;
typedef __attribute__((ext_vector_type(8))) __bf16 bf16x8;
typedef __attribute__((ext_vector_type(4))) _Float16 fp16x4;
typedef __attribute__((ext_vector_type(4))) float f32x4;
typedef long long i64;

#define H_IN 1342
#define TT   128
#define BB   128

static __device__ __forceinline__ f32x4 mfma16(bf16x8 a, bf16x8 b, f32x4 c) {
    return __builtin_amdgcn_mfma_f32_16x16x32_bf16(a, b, c, 0, 0, 0);
}
static __device__ __forceinline__ f32x4 mfma8(i64 a, i64 b, f32x4 c) {
    return __builtin_amdgcn_mfma_f32_16x16x32_fp8_fp8(a, b, c, 0, 0, 0);
}
static __device__ __forceinline__ float sigf(float x) {
    return 1.f / (1.f + __expf(-x));
}
static __device__ __forceinline__ float tanhfast(float x) {
    return 2.f / (1.f + __expf(-2.f * x)) - 1.f;
}

// float -> OCP e4m3fn with RNE (software path; packing + prologue only).
static __device__ __forceinline__ unsigned char f2e4m3(float x) {
    unsigned char sgn = (unsigned char)((__builtin_bit_cast(unsigned int, x) >> 24) & 0x80);
    float ax = fabsf(x);
    if (ax < 0.015625f) {
        float q = nearbyintf(ax * 512.f);
        return sgn | (unsigned char)(int)q;
    }
    if (ax >= 448.f) return sgn | 0x7E;
    int e; float m = frexpf(ax, &e);
    float q = nearbyintf(m * 16.f);
    int E = e - 1;
    if (q == 16.f) { q = 8.f; E += 1; }
    if (E > 8) return sgn | 0x7E;
    return sgn | (unsigned char)((E + 7) << 3) | (unsigned char)((int)q & 7);
}

static __device__ __forceinline__ unsigned int pk_fp8(float a, float b) {
#if __has_builtin(__builtin_amdgcn_cvt_pk_fp8_f32)
    return (unsigned int)__builtin_amdgcn_cvt_pk_fp8_f32(a, b, 0, false);
#else
    return (unsigned int)f2e4m3(a) | ((unsigned int)f2e4m3(b) << 8);
#endif
}

// ---------------------------------------------------------------------------
// Pack the three w_hh matrices (768x256) into fp8 MFMA B-fragment order.
// ---------------------------------------------------------------------------
__global__ void prep_pack2(const float* __restrict__ whh0,
                           const float* __restrict__ whh1,
                           const float* __restrict__ whh2,
                           unsigned char* __restrict__ Wh8)
{
    int idx = blockIdx.x * blockDim.x + threadIdx.x;
    if (idx < 589824) {
        int l = idx / 196608;
        int r = idx - l * 196608;
        const float* w = (l == 0) ? whh0 : (l == 1) ? whh1 : whh2;
        int f = r >> 9, q = r & 511;
        int lane = q >> 3, j = q & 7;
        int nt = f >> 3, kt = f & 7;
        int n = nt * 16 + (lane & 15);
        int k = kt * 32 + (lane >> 4) * 8 + j;
        Wh8[idx] = f2e4m3(w[n * 256 + k]);
    }
}

// ---------------------------------------------------------------------------
// gx tile layout, per (t, g): 32 KB at gxt + ((t*8+g)<<15):
//   r-plane fp16 [col][row16]   : off = col*32 + row*2          (col 0..255)
//   z-plane fp16 [col][row16]   : off = 8192 + col*32 + row*2
//   n-plane fp32 [col][row16]   : off = 16384 + col*64 + row*4
// b_hh folded into r,z; n carries b_ih only (bN added in gru).
// Shared epilogue: matrix rows rm = t*128 + b; thread's 4 r-values are
// rows 4lh..4lh+3 of group g=w at tile t=blockIdx.x -> ONE vector store.
// ---------------------------------------------------------------------------
// Layer-0 input GEMM (A rows remapped to t*128+b).
__global__ __launch_bounds__(512) void gemm_gx0(const float* __restrict__ X,
                                                const float* __restrict__ W,
                                                const float* __restrict__ bih,
                                                const float* __restrict__ bhh,
                                                char*  __restrict__ gxt)
{
    __shared__ bf16 As[128][40];
    __shared__ bf16 Bs[256][40];
    const int tid  = threadIdx.x;
    const int lane = tid & 63;
    const int w    = tid >> 6;
    const int cl   = lane & 15;
    const int lh   = lane >> 4;
    const int n0   = blockIdx.y * 256;

    f32x4 acc[16];
#pragma unroll
    for (int i = 0; i < 16; ++i) acc[i] = (f32x4){0.f, 0.f, 0.f, 0.f};

    for (int kt = 0; kt < 42; ++kt) {
        const int k0 = kt * 32;
        {   // A row (matrix row rm = blockIdx.x*128 + row): b=row, t=blockIdx.x
            int row = tid >> 2;
            int c   = (tid & 3) * 8;
            const float* src = X + ((size_t)row * 128 + blockIdx.x) * H_IN + (k0 + c);
            bf16x8 pk;
            if (k0 + c + 8 <= H_IN) {
                const float2* s2 = (const float2*)src;
                float2 v0 = s2[0], v1 = s2[1], v2 = s2[2], v3 = s2[3];
                pk[0] = (bf16)v0.x; pk[1] = (bf16)v0.y; pk[2] = (bf16)v1.x; pk[3] = (bf16)v1.y;
                pk[4] = (bf16)v2.x; pk[5] = (bf16)v2.y; pk[6] = (bf16)v3.x; pk[7] = (bf16)v3.y;
            } else {
#pragma unroll
                for (int i = 0; i < 8; ++i)
                    pk[i] = (bf16)((k0 + c + i < H_IN) ? src[i] : 0.f);
            }
            *(bf16x8*)&As[row][c] = pk;
        }
        {
            int row = tid >> 1;
            int c   = (tid & 1) * 16;
            const float* src = W + (size_t)(n0 + row) * H_IN + (k0 + c);
#pragma unroll
            for (int h = 0; h < 2; ++h) {
                const float* s = src + h * 8;
                bf16x8 pk;
                if (k0 + c + h * 8 + 8 <= H_IN) {
                    const float2* s2 = (const float2*)s;
                    float2 v0 = s2[0], v1 = s2[1], v2 = s2[2], v3 = s2[3];
                    pk[0] = (bf16)v0.x; pk[1] = (bf16)v0.y; pk[2] = (bf16)v1.x; pk[3] = (bf16)v1.y;
                    pk[4] = (bf16)v2.x; pk[5] = (bf16)v2.y; pk[6] = (bf16)v3.x; pk[7] = (bf16)v3.y;
                } else {
#pragma unroll
                    for (int i = 0; i < 8; ++i)
                        pk[i] = (bf16)((k0 + c + h * 8 + i < H_IN) ? s[i] : 0.f);
                }
                *(bf16x8*)&Bs[row][c + h * 8] = pk;
            }
        }
        __syncthreads();
        bf16x8 a = *(const bf16x8*)&As[w * 16 + cl][lh * 8];
#pragma unroll
        for (int nt = 0; nt < 16; ++nt) {
            bf16x8 b = *(const bf16x8*)&Bs[nt * 16 + cl][lh * 8];
            acc[nt] = mfma16(a, b, acc[nt]);
        }
        __syncthreads();
    }
    char* base = gxt + (((size_t)blockIdx.x * 8 + w) << 15);
#pragma unroll
    for (int nt = 0; nt < 16; ++nt) {
        const int col = n0 + nt * 16 + cl;
        if (col < 256) {
            fp16x4 pk;
#pragma unroll
            for (int r = 0; r < 4; ++r) pk[r] = (fp16)(acc[nt][r] + bih[col] + bhh[col]);
            *(fp16x4*)(base + col * 32 + 8 * lh) = pk;
        } else if (col < 512) {
            fp16x4 pk;
#pragma unroll
            for (int r = 0; r < 4; ++r) pk[r] = (fp16)(acc[nt][r] + bih[col] + bhh[col]);
            *(fp16x4*)(base + 8192 + (col - 256) * 32 + 8 * lh) = pk;
        } else {
            float4 pk = {acc[nt][0] + bih[col], acc[nt][1] + bih[col],
                         acc[nt][2] + bih[col], acc[nt][3] + bih[col]};
            *(float4*)(base + 16384 + (col - 512) * 64 + 16 * lh) = pk;
        }
    }
}

// Layers 1/2 input GEMM: A = Y bf16 [t*128+b][256]; same epilogue.
__global__ __launch_bounds__(512) void gemm_gxy(const bf16* __restrict__ Y,
                                                const float* __restrict__ W,
                                                const float* __restrict__ bih,
                                                const float* __restrict__ bhh,
                                                char*  __restrict__ gxt)
{
    __shared__ bf16 As[128][40];
    __shared__ bf16 Bs[256][40];
    const int tid  = threadIdx.x;
    const int lane = tid & 63;
    const int w    = tid >> 6;
    const int cl   = lane & 15;
    const int lh   = lane >> 4;
    const int rm0  = blockIdx.x * 128;
    const int n0   = blockIdx.y * 256;

    f32x4 acc[16];
#pragma unroll
    for (int i = 0; i < 16; ++i) acc[i] = (f32x4){0.f, 0.f, 0.f, 0.f};

    for (int kt = 0; kt < 8; ++kt) {
        const int k0 = kt * 32;
        {
            int row = tid >> 2;
            int c   = (tid & 3) * 8;
            *(bf16x8*)&As[row][c] =
                *(const bf16x8*)(Y + (size_t)(rm0 + row) * 256 + k0 + c);
        }
        {
            int row = tid >> 1;
            int c   = (tid & 1) * 16;
            const float* src = W + (size_t)(n0 + row) * 256 + (k0 + c);
#pragma unroll
            for (int h = 0; h < 2; ++h) {
                const float2* s2 = (const float2*)(src + h * 8);
                float2 v0 = s2[0], v1 = s2[1], v2 = s2[2], v3 = s2[3];
                bf16x8 pk;
                pk[0] = (bf16)v0.x; pk[1] = (bf16)v0.y; pk[2] = (bf16)v1.x; pk[3] = (bf16)v1.y;
                pk[4] = (bf16)v2.x; pk[5] = (bf16)v2.y; pk[6] = (bf16)v3.x; pk[7] = (bf16)v3.y;
                *(bf16x8*)&Bs[row][c + h * 8] = pk;
            }
        }
        __syncthreads();
        bf16x8 a = *(const bf16x8*)&As[w * 16 + cl][lh * 8];
#pragma unroll
        for (int nt = 0; nt < 16; ++nt) {
            bf16x8 b = *(const bf16x8*)&Bs[nt * 16 + cl][lh * 8];
            acc[nt] = mfma16(a, b, acc[nt]);
        }
        __syncthreads();
    }
    char* base = gxt + (((size_t)blockIdx.x * 8 + w) << 15);
#pragma unroll
    for (int nt = 0; nt < 16; ++nt) {
        const int col = n0 + nt * 16 + cl;
        if (col < 256) {
            fp16x4 pk;
#pragma unroll
            for (int r = 0; r < 4; ++r) pk[r] = (fp16)(acc[nt][r] + bih[col] + bhh[col]);
            *(fp16x4*)(base + col * 32 + 8 * lh) = pk;
        } else if (col < 512) {
            fp16x4 pk;
#pragma unroll
            for (int r = 0; r < 4; ++r) pk[r] = (fp16)(acc[nt][r] + bih[col] + bhh[col]);
            *(fp16x4*)(base + 8192 + (col - 256) * 32 + 8 * lh) = pk;
        } else {
            float4 pk = {acc[nt][0] + bih[col], acc[nt][1] + bih[col],
                         acc[nt][2] + bih[col], acc[nt][3] + bih[col]};
            *(float4*)(base + 16384 + (col - 512) * 64 + 16 * lh) = pk;
        }
    }
}

// ---------------------------------------------------------------------------
// Recurrent layer v12 = round-16 (one barrier, fp8 weights, db h tiles) +
// transposed gx tiles (6 vector LDS reads replace 16 scalar) + setprio.
// ---------------------------------------------------------------------------
__global__ __launch_bounds__(512)
void gru_rec(
    const char* __restrict__ gxt,           // [T][8][32KB] transposed gx tiles
    const unsigned char* __restrict__ Wh8,  // this layer's fp8 hh pack
    const float* __restrict__ bhh,          // raw b_hh (768); only n-part used
    const float* __restrict__ h0,           // hidden + l*128*256
    bf16*  __restrict__ Y,                  // [T*B][256] bf16 out
    float* __restrict__ hnfL)               // hnf + l*256 (stride 768)
{
    __shared__ unsigned char Ah8[2][16][264];          // fp8 h (MFMA A), db
    __shared__ bf16 Yst[2][16][264];                   // bf16 h (Y stage), db
    __shared__ __align__(16) char gxl[2][32768];       // transposed gx ring

    const int tid  = threadIdx.x;
    const int lane = tid & 63;
    const int w    = tid >> 6;              // 0..7
    const int cl   = lane & 15;
    const int lh   = lane >> 4;
    const int g    = blockIdx.x;

    // ---- 48 fp8 B-fragments -> registers (8 B each) ----
    i64 Br[2][8], Bz[2][8], Bn[2][8];
#pragma unroll
    for (int ji = 0; ji < 2; ++ji) {
        const int jt = 2 * w + ji;
#pragma unroll
        for (int kk = 0; kk < 8; ++kk) {
            Br[ji][kk] = *(const i64*)(Wh8 + (size_t)(( jt       * 8 + kk) * 512) + lane * 8);
            Bz[ji][kk] = *(const i64*)(Wh8 + (size_t)(((16 + jt) * 8 + kk) * 512) + lane * 8);
            Bn[ji][kk] = *(const i64*)(Wh8 + (size_t)(((32 + jt) * 8 + kk) * 512) + lane * 8);
        }
    }
    float bN[2];
#pragma unroll
    for (int ji = 0; ji < 2; ++ji)
        bN[ji] = bhh[512 + (2 * w + ji) * 16 + cl];

    // gx tile stage: wave w stages bytes [w*4096, w*4096+4096) linearly
    auto STAGE = [&](int tt, int slot) {
        const char* src = gxt + (((size_t)tt * 8 + g) << 15) + w * 4096 + lane * 16;
        char* dst = &gxl[slot][w * 4096];
#pragma unroll
        for (int i = 0; i < 4; ++i) {
            __builtin_amdgcn_global_load_lds(
                (const __attribute__((address_space(1))) void*)(src + i * 1024),
                (__attribute__((address_space(3))) void*)(dst + i * 1024), 16, 0, 0);
        }
    };

    // ---- prologue: h0 -> regs + Ah8[1]; issue tile 0 ----
    float hprev[2][4];
#pragma unroll
    for (int ji = 0; ji < 2; ++ji) {
        const int col = (2 * w + ji) * 16 + cl;
#pragma unroll
        for (int r = 0; r < 4; ++r) {
            const int m = 4 * lh + r;
            float v = h0[(size_t)(g * 16 + m) * 256 + col];
            hprev[ji][r] = v;
            Ah8[1][m][col] = f2e4m3(v);
        }
    }
    STAGE(0, 0);
    __syncthreads();   // one-time full drain (tile 0 + Ah8[1] staged)

    const int c0 = 32 * w + cl;
    const int c1 = c0 + 16;

    for (int t = 0; t < TT; ++t) {
        const int slot = t & 1;
        const int rb   = (t + 1) & 1;

        // ---- Y epilogue for step t-1 (store stays in flight) ----
        if (t > 0) {
            const int yrow = tid >> 5;
            const int yc   = (tid & 31) * 8;
            bf16x8 yv = *(const bf16x8*)&Yst[(t - 1) & 1][yrow][yc];
            *(bf16x8*)(Y + ((size_t)(t - 1) * BB + g * 16 + yrow) * 256 + yc) = yv;
        }
        // ---- issue next gx tile ----
        STAGE((t + 1 < TT) ? t + 1 : TT - 1, slot ^ 1);

        // ---- MFMA over Ah8[rb] (fp8) ----
        f32x4 cr[2], cz[2], cn[2];
#pragma unroll
        for (int i = 0; i < 2; ++i) {
            cr[i] = (f32x4){0.f,0.f,0.f,0.f};
            cz[i] = (f32x4){0.f,0.f,0.f,0.f};
            cn[i] = (f32x4){0.f,0.f,0.f,0.f};
        }
        __builtin_amdgcn_s_setprio(1);
#pragma unroll
        for (int kk = 0; kk < 8; ++kk) {
            i64 a = *(const i64*)&Ah8[rb][cl][kk * 32 + lh * 8];
#pragma unroll
            for (int ji = 0; ji < 2; ++ji) {
                cr[ji] = mfma8(a, Br[ji][kk], cr[ji]);
                cz[ji] = mfma8(a, Bz[ji][kk], cz[ji]);
                cn[ji] = mfma8(a, Bn[ji][kk], cn[ji]);
            }
        }
        __builtin_amdgcn_s_setprio(0);

        // ---- tile t ready? (newer ops: (t>0: 1 Y-store) + 4 next-tile loads) ----
        if (t == 0) asm volatile("s_waitcnt vmcnt(4)" ::: "memory");
        else        asm volatile("s_waitcnt vmcnt(5)" ::: "memory");
        __builtin_amdgcn_sched_barrier(0);

        // ---- gates: 6 vector LDS reads of transposed gx ----
        const char* gb = &gxl[slot][0];
        fp16x4 rv0 = *(const fp16x4*)(gb + c0 * 32 + 8 * lh);
        fp16x4 rv1 = *(const fp16x4*)(gb + c0 * 32 + 8 * lh + 512);
        fp16x4 zv0 = *(const fp16x4*)(gb + 8192 + c0 * 32 + 8 * lh);
        fp16x4 zv1 = *(const fp16x4*)(gb + 8192 + c0 * 32 + 8 * lh + 512);
        f32x4  nv0 = *(const f32x4*) (gb + 16384 + c0 * 64 + 16 * lh);
        f32x4  nv1 = *(const f32x4*) (gb + 16384 + c0 * 64 + 16 * lh + 1024);

        float hn2[2][4];
#pragma unroll
        for (int ji = 0; ji < 2; ++ji) {
            const int col = (ji == 0) ? c0 : c1;
#pragma unroll
            for (int r = 0; r < 4; ++r) {
                const int m = 4 * lh + r;
                float gr = (float)(ji ? rv1[r] : rv0[r]);
                float gz = (float)(ji ? zv1[r] : zv0[r]);
                float gn = ji ? nv1[r] : nv0[r];
                float rr_ = sigf(gr + cr[ji][r]);
                float zz  = sigf(gz + cz[ji][r]);
                float nn  = tanhfast(gn + rr_ * (cn[ji][r] + bN[ji]));
                float hnew = (1.f - zz) * nn + zz * hprev[ji][r];
                hprev[ji][r] = hnew;
                hn2[ji][r] = hnew;
                Yst[slot][m][col] = (bf16)hnew;
                if (t == TT - 1) hnfL[(size_t)(g * 16 + m) * 768 + col] = hnew;
            }
        }
#pragma unroll
        for (int r = 0; r < 4; ++r) {
            const int m = 4 * lh + r;
            unsigned int pk = pk_fp8(hn2[0][r], hn2[1][r]);
            Ah8[slot][m][c0] = (unsigned char)(pk & 0xff);
            Ah8[slot][m][c1] = (unsigned char)((pk >> 8) & 0xff);
        }

        asm volatile("s_waitcnt lgkmcnt(0)" ::: "memory");
        __builtin_amdgcn_sched_barrier(0);
        __builtin_amdgcn_s_barrier();          // the ONLY barrier per step
        __builtin_amdgcn_sched_barrier(0);
    }

    // ---- final Y epilogue ----
    {
        const int yrow = tid >> 5;
        const int yc   = (tid & 31) * 8;
        bf16x8 yv = *(const bf16x8*)&Yst[(TT - 1) & 1][yrow][yc];
        *(bf16x8*)(Y + ((size_t)(TT - 1) * BB + g * 16 + yrow) * 256 + yc) = yv;
    }
}

// ---------------------------------------------------------------------------
// FC head as MFMA GEMM: out[b][n] = fc_b[n] + hn[b] . fc_w[n]
// M=128, N=1342 (6 tiles of 256), K=768.
// ---------------------------------------------------------------------------
__global__ __launch_bounds__(512) void fc_gemm(const float* __restrict__ hn,
                                               const float* __restrict__ fcw,
                                               const float* __restrict__ fcb,
                                               float* __restrict__ out)
{
    __shared__ bf16 As[128][40];
    __shared__ bf16 Bs[256][40];
    const int tid  = threadIdx.x;
    const int lane = tid & 63;
    const int w    = tid >> 6;
    const int cl   = lane & 15;
    const int lh   = lane >> 4;
    const int n0   = blockIdx.x * 256;

    f32x4 acc[16];
#pragma unroll
    for (int i = 0; i < 16; ++i) acc[i] = (f32x4){0.f, 0.f, 0.f, 0.f};

    for (int kt = 0; kt < 24; ++kt) {
        const int k0 = kt * 32;
        {
            int row = tid >> 2;
            int c   = (tid & 3) * 8;
            const float2* s2 = (const float2*)(hn + (size_t)row * 768 + k0 + c);
            float2 v0 = s2[0], v1 = s2[1], v2 = s2[2], v3 = s2[3];
            bf16x8 pk;
            pk[0] = (bf16)v0.x; pk[1] = (bf16)v0.y; pk[2] = (bf16)v1.x; pk[3] = (bf16)v1.y;
            pk[4] = (bf16)v2.x; pk[5] = (bf16)v2.y; pk[6] = (bf16)v3.x; pk[7] = (bf16)v3.y;
            *(bf16x8*)&As[row][c] = pk;
        }
        {
            int row = tid >> 1;
            int c   = (tid & 1) * 16;
            const int n = n0 + row;
#pragma unroll
            for (int h = 0; h < 2; ++h) {
                bf16x8 pk;
                if (n < H_IN) {
                    const float2* s2 = (const float2*)(fcw + (size_t)n * 768 + k0 + c + h * 8);
                    float2 v0 = s2[0], v1 = s2[1], v2 = s2[2], v3 = s2[3];
                    pk[0] = (bf16)v0.x; pk[1] = (bf16)v0.y; pk[2] = (bf16)v1.x; pk[3] = (bf16)v1.y;
                    pk[4] = (bf16)v2.x; pk[5] = (bf16)v2.y; pk[6] = (bf16)v3.x; pk[7] = (bf16)v3.y;
                } else {
#pragma unroll
                    for (int i = 0; i < 8; ++i) pk[i] = (bf16)0.f;
                }
                *(bf16x8*)&Bs[row][c + h * 8] = pk;
            }
        }
        __syncthreads();
        bf16x8 a = *(const bf16x8*)&As[w * 16 + cl][lh * 8];
#pragma unroll
        for (int nt = 0; nt < 16; ++nt) {
            bf16x8 b = *(const bf16x8*)&Bs[nt * 16 + cl][lh * 8];
            acc[nt] = mfma16(a, b, acc[nt]);
        }
        __syncthreads();
    }
#pragma unroll
    for (int nt = 0; nt < 16; ++nt) {
#pragma unroll
        for (int r = 0; r < 4; ++r) {
            int b   = w * 16 + 4 * lh + r;
            int col = n0 + nt * 16 + cl;
            if (col < H_IN)
                out[(size_t)b * H_IN + col] = acc[nt][r] + fcb[col];
        }
    }
}

extern "C" void kernel_launch(void* const* d_in, const int* in_sizes, int n_in,
                              void* d_out, int out_size, void* d_ws, size_t ws_size,
                              hipStream_t stream) {
    const float* X    = (const float*)d_in[0];
    const float* hid  = (const float*)d_in[1];
    const float* wih0 = (const float*)d_in[2];
    const float* whh0 = (const float*)d_in[3];
    const float* bih0 = (const float*)d_in[4];
    const float* bhh0 = (const float*)d_in[5];
    const float* wih1 = (const float*)d_in[6];
    const float* whh1 = (const float*)d_in[7];
    const float* bih1 = (const float*)d_in[8];
    const float* bhh1 = (const float*)d_in[9];
    const float* wih2 = (const float*)d_in[10];
    const float* whh2 = (const float*)d_in[11];
    const float* bih2 = (const float*)d_in[12];
    const float* bhh2 = (const float*)d_in[13];
    const float* fcw  = (const float*)d_in[14];
    const float* fcb  = (const float*)d_in[15];
    float* out = (float*)d_out;

    // Layout (total 43,525,120 B — within the known-safe 52.7 MB):
    char* ws = (char*)d_ws;
    unsigned char* Wh8 = (unsigned char*)ws;       //          0 ..   589,824
    float* hnf   = (float*)(ws + 1188864);         //  1,188,864 .. 1,582,080
    bf16*  Y     = (bf16*)(ws + 1582080);          //  1,582,080 .. 9,970,688
    char*  gxt   = ws + 9970688;                   //  9,970,688 .. 43,525,120 (33.55 MB)

    prep_pack2<<<dim3(1152), dim3(512), 0, stream>>>(whh0, whh1, whh2, Wh8);
    // layer 0
    gemm_gx0<<<dim3(128, 3), dim3(512), 0, stream>>>(X, wih0, bih0, bhh0, gxt);
    gru_rec<<<dim3(8), dim3(512), 0, stream>>>(gxt, Wh8, bhh0, hid, Y, hnf);
    // layer 1
    gemm_gxy<<<dim3(128, 3), dim3(512), 0, stream>>>(Y, wih1, bih1, bhh1, gxt);
    gru_rec<<<dim3(8), dim3(512), 0, stream>>>(gxt, Wh8 + 196608, bhh1,
                                               hid + 32768, Y, hnf + 256);
    // layer 2
    gemm_gxy<<<dim3(128, 3), dim3(512), 0, stream>>>(Y, wih2, bih2, bhh2, gxt);
    gru_rec<<<dim3(8), dim3(512), 0, stream>>>(gxt, Wh8 + 393216, bhh2,
                                               hid + 65536, Y, hnf + 512);
    // head
    fc_gemm<<<dim3(6), dim3(512), 0, stream>>>(hnf, fcw, fcb, out);
    hipMemcpyAsync(out + 171776, hid, 98304 * sizeof(float),
                   hipMemcpyDeviceToDevice, stream);
}

// Round 18
// 1167.166 us; speedup vs baseline: 2.1897x; 1.0888x over previous
//
#include <hip/hip_runtime.h>
#include <hip/hip_bf16.h>

typedef __bf16 bf16;
typedef _Float16 fp16;
typedef __attribute__((ext_vector_type(8))) __bf16 bf16x8;
typedef __attribute__((ext_vector_type(4))) __bf16 bf16x4;
typedef __attribute__((ext_vector_type(4))) _Float16 fp16x4;
typedef __attribute__((ext_vector_type(4))) float f32x4;
typedef long long i64;

#define H_IN 1342
#define TT   128
#define BB   128

static __device__ __forceinline__ f32x4 mfma16(bf16x8 a, bf16x8 b, f32x4 c) {
    return __builtin_amdgcn_mfma_f32_16x16x32_bf16(a, b, c, 0, 0, 0);
}
static __device__ __forceinline__ f32x4 mfma8(i64 a, i64 b, f32x4 c) {
    return __builtin_amdgcn_mfma_f32_16x16x32_fp8_fp8(a, b, c, 0, 0, 0);
}
static __device__ __forceinline__ float sigf(float x) {
    return 1.f / (1.f + __expf(-x));
}
static __device__ __forceinline__ float tanhfast(float x) {
    return 2.f / (1.f + __expf(-2.f * x)) - 1.f;
}

// float -> OCP e4m3fn with RNE (software path; packing + prologue only).
static __device__ __forceinline__ unsigned char f2e4m3(float x) {
    unsigned char sgn = (unsigned char)((__builtin_bit_cast(unsigned int, x) >> 24) & 0x80);
    float ax = fabsf(x);
    if (ax < 0.015625f) {
        float q = nearbyintf(ax * 512.f);
        return sgn | (unsigned char)(int)q;
    }
    if (ax >= 448.f) return sgn | 0x7E;
    int e; float m = frexpf(ax, &e);
    float q = nearbyintf(m * 16.f);
    int E = e - 1;
    if (q == 16.f) { q = 8.f; E += 1; }
    if (E > 8) return sgn | 0x7E;
    return sgn | (unsigned char)((E + 7) << 3) | (unsigned char)((int)q & 7);
}

static __device__ __forceinline__ unsigned int pk_fp8(float a, float b) {
#if __has_builtin(__builtin_amdgcn_cvt_pk_fp8_f32)
    return (unsigned int)__builtin_amdgcn_cvt_pk_fp8_f32(a, b, 0, false);
#else
    return (unsigned int)f2e4m3(a) | ((unsigned int)f2e4m3(b) << 8);
#endif
}

// ---------------------------------------------------------------------------
// Pack the three w_hh matrices (768x256) into fp8 MFMA B-fragment order.
// ---------------------------------------------------------------------------
__global__ void prep_pack2(const float* __restrict__ whh0,
                           const float* __restrict__ whh1,
                           const float* __restrict__ whh2,
                           unsigned char* __restrict__ Wh8)
{
    int idx = blockIdx.x * blockDim.x + threadIdx.x;
    if (idx < 589824) {
        int l = idx / 196608;
        int r = idx - l * 196608;
        const float* w = (l == 0) ? whh0 : (l == 1) ? whh1 : whh2;
        int f = r >> 9, q = r & 511;
        int lane = q >> 3, j = q & 7;
        int nt = f >> 3, kt = f & 7;
        int n = nt * 16 + (lane & 15);
        int k = kt * 32 + (lane >> 4) * 8 + j;
        Wh8[idx] = f2e4m3(w[n * 256 + k]);
    }
}

// ---------------------------------------------------------------------------
// gx tile layout, per (t, g): 32 KB at gxt + ((t*8+g)<<15):
//   r-plane fp16 [col][row16] : off = col*32 + row*2
//   z-plane fp16 [col][row16] : off = 8192 + col*32 + row*2
//   n-plane fp32 [col][row16] : off = 16384 + col*64 + row*4
// ---------------------------------------------------------------------------
__global__ __launch_bounds__(512) void gemm_gx0(const float* __restrict__ X,
                                                const float* __restrict__ W,
                                                const float* __restrict__ bih,
                                                const float* __restrict__ bhh,
                                                char*  __restrict__ gxt)
{
    __shared__ bf16 As[128][40];
    __shared__ bf16 Bs[256][40];
    const int tid  = threadIdx.x;
    const int lane = tid & 63;
    const int w    = tid >> 6;
    const int cl   = lane & 15;
    const int lh   = lane >> 4;
    const int n0   = blockIdx.y * 256;

    f32x4 acc[16];
#pragma unroll
    for (int i = 0; i < 16; ++i) acc[i] = (f32x4){0.f, 0.f, 0.f, 0.f};

    for (int kt = 0; kt < 42; ++kt) {
        const int k0 = kt * 32;
        {   // A row rm = blockIdx.x*128 + row -> b=row, t=blockIdx.x
            int row = tid >> 2;
            int c   = (tid & 3) * 8;
            const float* src = X + ((size_t)row * 128 + blockIdx.x) * H_IN + (k0 + c);
            bf16x8 pk;
            if (k0 + c + 8 <= H_IN) {
                const float2* s2 = (const float2*)src;
                float2 v0 = s2[0], v1 = s2[1], v2 = s2[2], v3 = s2[3];
                pk[0] = (bf16)v0.x; pk[1] = (bf16)v0.y; pk[2] = (bf16)v1.x; pk[3] = (bf16)v1.y;
                pk[4] = (bf16)v2.x; pk[5] = (bf16)v2.y; pk[6] = (bf16)v3.x; pk[7] = (bf16)v3.y;
            } else {
#pragma unroll
                for (int i = 0; i < 8; ++i)
                    pk[i] = (bf16)((k0 + c + i < H_IN) ? src[i] : 0.f);
            }
            *(bf16x8*)&As[row][c] = pk;
        }
        {
            int row = tid >> 1;
            int c   = (tid & 1) * 16;
            const float* src = W + (size_t)(n0 + row) * H_IN + (k0 + c);
#pragma unroll
            for (int h = 0; h < 2; ++h) {
                const float* s = src + h * 8;
                bf16x8 pk;
                if (k0 + c + h * 8 + 8 <= H_IN) {
                    const float2* s2 = (const float2*)s;
                    float2 v0 = s2[0], v1 = s2[1], v2 = s2[2], v3 = s2[3];
                    pk[0] = (bf16)v0.x; pk[1] = (bf16)v0.y; pk[2] = (bf16)v1.x; pk[3] = (bf16)v1.y;
                    pk[4] = (bf16)v2.x; pk[5] = (bf16)v2.y; pk[6] = (bf16)v3.x; pk[7] = (bf16)v3.y;
                } else {
#pragma unroll
                    for (int i = 0; i < 8; ++i)
                        pk[i] = (bf16)((k0 + c + h * 8 + i < H_IN) ? s[i] : 0.f);
                }
                *(bf16x8*)&Bs[row][c + h * 8] = pk;
            }
        }
        __syncthreads();
        bf16x8 a = *(const bf16x8*)&As[w * 16 + cl][lh * 8];
#pragma unroll
        for (int nt = 0; nt < 16; ++nt) {
            bf16x8 b = *(const bf16x8*)&Bs[nt * 16 + cl][lh * 8];
            acc[nt] = mfma16(a, b, acc[nt]);
        }
        __syncthreads();
    }
    char* base = gxt + (((size_t)blockIdx.x * 8 + w) << 15);
#pragma unroll
    for (int nt = 0; nt < 16; ++nt) {
        const int col = n0 + nt * 16 + cl;
        if (col < 256) {
            fp16x4 pk;
#pragma unroll
            for (int r = 0; r < 4; ++r) pk[r] = (fp16)(acc[nt][r] + bih[col] + bhh[col]);
            *(fp16x4*)(base + col * 32 + 8 * lh) = pk;
        } else if (col < 512) {
            fp16x4 pk;
#pragma unroll
            for (int r = 0; r < 4; ++r) pk[r] = (fp16)(acc[nt][r] + bih[col] + bhh[col]);
            *(fp16x4*)(base + 8192 + (col - 256) * 32 + 8 * lh) = pk;
        } else {
            float4 pk = {acc[nt][0] + bih[col], acc[nt][1] + bih[col],
                         acc[nt][2] + bih[col], acc[nt][3] + bih[col]};
            *(float4*)(base + 16384 + (col - 512) * 64 + 16 * lh) = pk;
        }
    }
}

// Layers 1/2 input GEMM: A = Y bf16 [t*128+b][256]; same epilogue.
__global__ __launch_bounds__(512) void gemm_gxy(const bf16* __restrict__ Y,
                                                const float* __restrict__ W,
                                                const float* __restrict__ bih,
                                                const float* __restrict__ bhh,
                                                char*  __restrict__ gxt)
{
    __shared__ bf16 As[128][40];
    __shared__ bf16 Bs[256][40];
    const int tid  = threadIdx.x;
    const int lane = tid & 63;
    const int w    = tid >> 6;
    const int cl   = lane & 15;
    const int lh   = lane >> 4;
    const int rm0  = blockIdx.x * 128;
    const int n0   = blockIdx.y * 256;

    f32x4 acc[16];
#pragma unroll
    for (int i = 0; i < 16; ++i) acc[i] = (f32x4){0.f, 0.f, 0.f, 0.f};

    for (int kt = 0; kt < 8; ++kt) {
        const int k0 = kt * 32;
        {
            int row = tid >> 2;
            int c   = (tid & 3) * 8;
            *(bf16x8*)&As[row][c] =
                *(const bf16x8*)(Y + (size_t)(rm0 + row) * 256 + k0 + c);
        }
        {
            int row = tid >> 1;
            int c   = (tid & 1) * 16;
            const float* src = W + (size_t)(n0 + row) * 256 + (k0 + c);
#pragma unroll
            for (int h = 0; h < 2; ++h) {
                const float2* s2 = (const float2*)(src + h * 8);
                float2 v0 = s2[0], v1 = s2[1], v2 = s2[2], v3 = s2[3];
                bf16x8 pk;
                pk[0] = (bf16)v0.x; pk[1] = (bf16)v0.y; pk[2] = (bf16)v1.x; pk[3] = (bf16)v1.y;
                pk[4] = (bf16)v2.x; pk[5] = (bf16)v2.y; pk[6] = (bf16)v3.x; pk[7] = (bf16)v3.y;
                *(bf16x8*)&Bs[row][c + h * 8] = pk;
            }
        }
        __syncthreads();
        bf16x8 a = *(const bf16x8*)&As[w * 16 + cl][lh * 8];
#pragma unroll
        for (int nt = 0; nt < 16; ++nt) {
            bf16x8 b = *(const bf16x8*)&Bs[nt * 16 + cl][lh * 8];
            acc[nt] = mfma16(a, b, acc[nt]);
        }
        __syncthreads();
    }
    char* base = gxt + (((size_t)blockIdx.x * 8 + w) << 15);
#pragma unroll
    for (int nt = 0; nt < 16; ++nt) {
        const int col = n0 + nt * 16 + cl;
        if (col < 256) {
            fp16x4 pk;
#pragma unroll
            for (int r = 0; r < 4; ++r) pk[r] = (fp16)(acc[nt][r] + bih[col] + bhh[col]);
            *(fp16x4*)(base + col * 32 + 8 * lh) = pk;
        } else if (col < 512) {
            fp16x4 pk;
#pragma unroll
            for (int r = 0; r < 4; ++r) pk[r] = (fp16)(acc[nt][r] + bih[col] + bhh[col]);
            *(fp16x4*)(base + 8192 + (col - 256) * 32 + 8 * lh) = pk;
        } else {
            float4 pk = {acc[nt][0] + bih[col], acc[nt][1] + bih[col],
                         acc[nt][2] + bih[col], acc[nt][3] + bih[col]};
            *(float4*)(base + 16384 + (col - 512) * 64 + 16 * lh) = pk;
        }
    }
}

// ---------------------------------------------------------------------------
// Recurrent layer v13: 1024 threads / 16 waves; wave w owns ONE col-tile
// (cols 16w..16w+15) x 3 gates = 24 fp8 B-frags = 48 VGPRs -> the resident
// set (~92 regs) fits the 128-reg budget that 16 waves/CU forces; 4 waves/
// SIMD absorb LDS/trans latency in the skewed one-barrier schedule.
// ---------------------------------------------------------------------------
__global__ __launch_bounds__(1024)
void gru_rec(
    const char* __restrict__ gxt,           // [T][8][32KB] transposed gx tiles
    const unsigned char* __restrict__ Wh8,  // this layer's fp8 hh pack
    const float* __restrict__ bhh,          // raw b_hh (768); only n-part used
    const float* __restrict__ h0,           // hidden + l*128*256
    bf16*  __restrict__ Y,                  // [T*B][256] bf16 out
    float* __restrict__ hnfL)               // hnf + l*256 (stride 768)
{
    __shared__ unsigned char Ah8[2][16][264];          // fp8 h (MFMA A), db
    __shared__ bf16 Yst[2][16][264];                   // bf16 h (Y stage), db
    __shared__ __align__(16) char gxl[2][32768];       // transposed gx ring

    const int tid  = threadIdx.x;
    const int lane = tid & 63;
    const int w    = tid >> 6;              // 0..15 == col-tile
    const int cl   = lane & 15;
    const int lh   = lane >> 4;
    const int g    = blockIdx.x;
    const int col  = 16 * w + cl;

    // ---- 24 fp8 B-fragments (one col-tile, 3 gates) -> registers ----
    i64 Br[8], Bz[8], Bn[8];
#pragma unroll
    for (int kk = 0; kk < 8; ++kk) {
        Br[kk] = *(const i64*)(Wh8 + (size_t)(( w       * 8 + kk) * 512) + lane * 8);
        Bz[kk] = *(const i64*)(Wh8 + (size_t)(((16 + w) * 8 + kk) * 512) + lane * 8);
        Bn[kk] = *(const i64*)(Wh8 + (size_t)(((32 + w) * 8 + kk) * 512) + lane * 8);
    }
    const float bN = bhh[512 + col];

    // gx tile stage: wave w stages bytes [w*2048, w*2048+2048)
    auto STAGE = [&](int tt, int slot) {
        const char* src = gxt + (((size_t)tt * 8 + g) << 15) + w * 2048 + lane * 16;
        char* dst = &gxl[slot][w * 2048];
#pragma unroll
        for (int i = 0; i < 2; ++i) {
            __builtin_amdgcn_global_load_lds(
                (const __attribute__((address_space(1))) void*)(src + i * 1024),
                (__attribute__((address_space(3))) void*)(dst + i * 1024), 16, 0, 0);
        }
    };

    // ---- prologue: h0 -> regs + Ah8[1]; issue tile 0 ----
    float hprev[4];
#pragma unroll
    for (int r = 0; r < 4; ++r) {
        const int m = 4 * lh + r;
        float v = h0[(size_t)(g * 16 + m) * 256 + col];
        hprev[r] = v;
        Ah8[1][m][col] = f2e4m3(v);
    }
    STAGE(0, 0);
    __syncthreads();   // one-time full drain (tile 0 + Ah8[1] staged)

    for (int t = 0; t < TT; ++t) {
        const int slot = t & 1;
        const int rb   = (t + 1) & 1;

        // ---- Y epilogue for step t-1 (store stays in flight) ----
        if (t > 0) {
            const int yrow = tid >> 6;          // 0..15
            const int yc   = (tid & 63) * 4;    // 0..252
            bf16x4 yv = *(const bf16x4*)&Yst[(t - 1) & 1][yrow][yc];
            *(bf16x4*)(Y + ((size_t)(t - 1) * BB + g * 16 + yrow) * 256 + yc) = yv;
        }
        // ---- issue next gx tile ----
        STAGE((t + 1 < TT) ? t + 1 : TT - 1, slot ^ 1);

        // ---- MFMA over Ah8[rb] (fp8) ----
        f32x4 cr = (f32x4){0.f,0.f,0.f,0.f};
        f32x4 cz = (f32x4){0.f,0.f,0.f,0.f};
        f32x4 cn = (f32x4){0.f,0.f,0.f,0.f};
        __builtin_amdgcn_s_setprio(1);
#pragma unroll
        for (int kk = 0; kk < 8; ++kk) {
            i64 a = *(const i64*)&Ah8[rb][cl][kk * 32 + lh * 8];
            cr = mfma8(a, Br[kk], cr);
            cz = mfma8(a, Bz[kk], cz);
            cn = mfma8(a, Bn[kk], cn);
        }
        __builtin_amdgcn_s_setprio(0);

        // ---- tile t ready? newer ops: (t>0: 1 Y-store) + 2 next-tile loads ----
        if (t == 0) asm volatile("s_waitcnt vmcnt(2)" ::: "memory");
        else        asm volatile("s_waitcnt vmcnt(3)" ::: "memory");
        __builtin_amdgcn_sched_barrier(0);

        // ---- gates: 3 vector LDS reads of transposed gx ----
        const char* gb = &gxl[slot][0];
        fp16x4 rv = *(const fp16x4*)(gb + col * 32 + 8 * lh);
        fp16x4 zv = *(const fp16x4*)(gb + 8192 + col * 32 + 8 * lh);
        f32x4  nv = *(const f32x4*) (gb + 16384 + col * 64 + 16 * lh);

        float hn4[4];
#pragma unroll
        for (int r = 0; r < 4; ++r) {
            const int m = 4 * lh + r;
            float rr_ = sigf((float)rv[r] + cr[r]);
            float zz  = sigf((float)zv[r] + cz[r]);
            float nn  = tanhfast(nv[r] + rr_ * (cn[r] + bN));
            float hnew = (1.f - zz) * nn + zz * hprev[r];
            hprev[r] = hnew;
            hn4[r] = hnew;
            Yst[slot][m][col] = (bf16)hnew;
            if (t == TT - 1) hnfL[(size_t)(g * 16 + m) * 768 + col] = hnew;
        }
        // fp8 h writes (hardware packed conversion, byte extract)
        {
            unsigned int p0 = pk_fp8(hn4[0], hn4[1]);
            unsigned int p1 = pk_fp8(hn4[2], hn4[3]);
            const int m0 = 4 * lh;
            Ah8[slot][m0 + 0][col] = (unsigned char)(p0 & 0xff);
            Ah8[slot][m0 + 1][col] = (unsigned char)((p0 >> 8) & 0xff);
            Ah8[slot][m0 + 2][col] = (unsigned char)(p1 & 0xff);
            Ah8[slot][m0 + 3][col] = (unsigned char)((p1 >> 8) & 0xff);
        }

        asm volatile("s_waitcnt lgkmcnt(0)" ::: "memory");
        __builtin_amdgcn_sched_barrier(0);
        __builtin_amdgcn_s_barrier();          // the ONLY barrier per step
        __builtin_amdgcn_sched_barrier(0);
    }

    // ---- final Y epilogue ----
    {
        const int yrow = tid >> 6;
        const int yc   = (tid & 63) * 4;
        bf16x4 yv = *(const bf16x4*)&Yst[(TT - 1) & 1][yrow][yc];
        *(bf16x4*)(Y + ((size_t)(TT - 1) * BB + g * 16 + yrow) * 256 + yc) = yv;
    }
}

// ---------------------------------------------------------------------------
// FC head as MFMA GEMM: out[b][n] = fc_b[n] + hn[b] . fc_w[n]
// ---------------------------------------------------------------------------
__global__ __launch_bounds__(512) void fc_gemm(const float* __restrict__ hn,
                                               const float* __restrict__ fcw,
                                               const float* __restrict__ fcb,
                                               float* __restrict__ out)
{
    __shared__ bf16 As[128][40];
    __shared__ bf16 Bs[256][40];
    const int tid  = threadIdx.x;
    const int lane = tid & 63;
    const int w    = tid >> 6;
    const int cl   = lane & 15;
    const int lh   = lane >> 4;
    const int n0   = blockIdx.x * 256;

    f32x4 acc[16];
#pragma unroll
    for (int i = 0; i < 16; ++i) acc[i] = (f32x4){0.f, 0.f, 0.f, 0.f};

    for (int kt = 0; kt < 24; ++kt) {
        const int k0 = kt * 32;
        {
            int row = tid >> 2;
            int c   = (tid & 3) * 8;
            const float2* s2 = (const float2*)(hn + (size_t)row * 768 + k0 + c);
            float2 v0 = s2[0], v1 = s2[1], v2 = s2[2], v3 = s2[3];
            bf16x8 pk;
            pk[0] = (bf16)v0.x; pk[1] = (bf16)v0.y; pk[2] = (bf16)v1.x; pk[3] = (bf16)v1.y;
            pk[4] = (bf16)v2.x; pk[5] = (bf16)v2.y; pk[6] = (bf16)v3.x; pk[7] = (bf16)v3.y;
            *(bf16x8*)&As[row][c] = pk;
        }
        {
            int row = tid >> 1;
            int c   = (tid & 1) * 16;
            const int n = n0 + row;
#pragma unroll
            for (int h = 0; h < 2; ++h) {
                bf16x8 pk;
                if (n < H_IN) {
                    const float2* s2 = (const float2*)(fcw + (size_t)n * 768 + k0 + c + h * 8);
                    float2 v0 = s2[0], v1 = s2[1], v2 = s2[2], v3 = s2[3];
                    pk[0] = (bf16)v0.x; pk[1] = (bf16)v0.y; pk[2] = (bf16)v1.x; pk[3] = (bf16)v1.y;
                    pk[4] = (bf16)v2.x; pk[5] = (bf16)v2.y; pk[6] = (bf16)v3.x; pk[7] = (bf16)v3.y;
                } else {
#pragma unroll
                    for (int i = 0; i < 8; ++i) pk[i] = (bf16)0.f;
                }
                *(bf16x8*)&Bs[row][c + h * 8] = pk;
            }
        }
        __syncthreads();
        bf16x8 a = *(const bf16x8*)&As[w * 16 + cl][lh * 8];
#pragma unroll
        for (int nt = 0; nt < 16; ++nt) {
            bf16x8 b = *(const bf16x8*)&Bs[nt * 16 + cl][lh * 8];
            acc[nt] = mfma16(a, b, acc[nt]);
        }
        __syncthreads();
    }
#pragma unroll
    for (int nt = 0; nt < 16; ++nt) {
#pragma unroll
        for (int r = 0; r < 4; ++r) {
            int b   = w * 16 + 4 * lh + r;
            int col = n0 + nt * 16 + cl;
            if (col < H_IN)
                out[(size_t)b * H_IN + col] = acc[nt][r] + fcb[col];
        }
    }
}

extern "C" void kernel_launch(void* const* d_in, const int* in_sizes, int n_in,
                              void* d_out, int out_size, void* d_ws, size_t ws_size,
                              hipStream_t stream) {
    const float* X    = (const float*)d_in[0];
    const float* hid  = (const float*)d_in[1];
    const float* wih0 = (const float*)d_in[2];
    const float* whh0 = (const float*)d_in[3];
    const float* bih0 = (const float*)d_in[4];
    const float* bhh0 = (const float*)d_in[5];
    const float* wih1 = (const float*)d_in[6];
    const float* whh1 = (const float*)d_in[7];
    const float* bih1 = (const float*)d_in[8];
    const float* bhh1 = (const float*)d_in[9];
    const float* wih2 = (const float*)d_in[10];
    const float* whh2 = (const float*)d_in[11];
    const float* bih2 = (const float*)d_in[12];
    const float* bhh2 = (const float*)d_in[13];
    const float* fcw  = (const float*)d_in[14];
    const float* fcb  = (const float*)d_in[15];
    float* out = (float*)d_out;

    // Layout (total 43,525,120 B — within the known-safe 52.7 MB):
    char* ws = (char*)d_ws;
    unsigned char* Wh8 = (unsigned char*)ws;       //          0 ..   589,824
    float* hnf   = (float*)(ws + 1188864);         //  1,188,864 .. 1,582,080
    bf16*  Y     = (bf16*)(ws + 1582080);          //  1,582,080 .. 9,970,688
    char*  gxt   = ws + 9970688;                   //  9,970,688 .. 43,525,120 (33.55 MB)

    prep_pack2<<<dim3(1152), dim3(512), 0, stream>>>(whh0, whh1, whh2, Wh8);
    // layer 0
    gemm_gx0<<<dim3(128, 3), dim3(512), 0, stream>>>(X, wih0, bih0, bhh0, gxt);
    gru_rec<<<dim3(8), dim3(1024), 0, stream>>>(gxt, Wh8, bhh0, hid, Y, hnf);
    // layer 1
    gemm_gxy<<<dim3(128, 3), dim3(512), 0, stream>>>(Y, wih1, bih1, bhh1, gxt);
    gru_rec<<<dim3(8), dim3(1024), 0, stream>>>(gxt, Wh8 + 196608, bhh1,
                                                hid + 32768, Y, hnf + 256);
    // layer 2
    gemm_gxy<<<dim3(128, 3), dim3(512), 0, stream>>>(Y, wih2, bih2, bhh2, gxt);
    gru_rec<<<dim3(8), dim3(1024), 0, stream>>>(gxt, Wh8 + 393216, bhh2,
                                                hid + 65536, Y, hnf + 512);
    // head
    fc_gemm<<<dim3(6), dim3(512), 0, stream>>>(hnf, fcw, fcb, out);
    hipMemcpyAsync(out + 171776, hid, 98304 * sizeof(float),
                   hipMemcpyDeviceToDevice, stream);
}